// Round 15
// baseline (222.154 us; speedup 1.0000x reference)
//
#include <hip/hip_runtime.h>
#include <hip/hip_bf16.h>
#include <cstdint>

#define T_TOK 8192
#define HID   1024
#define NE    9
#define ISZ   512
#define RBASE 18432
#define NSLOT (RBASE + T_TOK)   // 26624

#define BM 256
#define NROWB (NSLOT / BM)      // 104

typedef unsigned short u16;
typedef unsigned int   u32;
typedef signed char    i8;
typedef __attribute__((ext_vector_type(8))) short short8;
typedef __attribute__((ext_vector_type(4))) float f32x4;
typedef __attribute__((ext_vector_type(4))) int   i32x4;

__device__ __forceinline__ u16 f2bf(float f) {
  u32 u = __builtin_bit_cast(u32, f);
  return (u16)((u + 0x7fffu + ((u >> 16) & 1u)) >> 16);
}
__device__ __forceinline__ float bf2f(u16 v) {
  return __builtin_bit_cast(float, (u32)v << 16);
}
__device__ __forceinline__ int q8(float v, float inv) {
  int q = (int)__builtin_rintf(v * inv);
  return (q > 127) ? 127 : ((q < -127) ? -127 : q);
}
__device__ __forceinline__ int colp_of(int c) {
  int i = (c < 512) ? c : (c - 512);
  return (i >> 4) * 32 + ((c < 512) ? 0 : 16) + (i & 15);
}

#define STAGE(gp, lp) __builtin_amdgcn_global_load_lds( \
    (__attribute__((address_space(1))) u32*)(gp),       \
    (__attribute__((address_space(3))) u32*)(lp), 16, 0, 0)

// ---------------- per-column weight amax, stage 1: coalesced partials ----------
__global__ __launch_bounds__(256) void k_wamax_part(
    const float* __restrict__ wgu, const float* __restrict__ wsg,
    float* __restrict__ pmax) {
  const int e = blockIdx.y, hb = blockIdx.x;
  const float* src = (e < 8) ? (wgu + (size_t)e * 1048576) : wsg;
  const int wv = threadIdx.x >> 6, l = threadIdx.x & 63;
  float4 m4[4];
#pragma unroll
  for (int j = 0; j < 4; ++j) m4[j] = make_float4(0.f, 0.f, 0.f, 0.f);
  const int r0 = hb * 16 + wv * 4;
#pragma unroll
  for (int r = 0; r < 4; ++r) {
    const float* row = src + (size_t)(r0 + r) * 1024;
#pragma unroll
    for (int j = 0; j < 4; ++j) {
      const float4 v = *(const float4*)&row[j * 256 + l * 4];
      m4[j].x = fmaxf(m4[j].x, fabsf(v.x));
      m4[j].y = fmaxf(m4[j].y, fabsf(v.y));
      m4[j].z = fmaxf(m4[j].z, fabsf(v.z));
      m4[j].w = fmaxf(m4[j].w, fabsf(v.w));
    }
  }
  __shared__ float4 red[4][4][64];
#pragma unroll
  for (int j = 0; j < 4; ++j) red[wv][j][l] = m4[j];
  __syncthreads();
  const int j2 = threadIdx.x >> 6, l2 = threadIdx.x & 63;
  const float4 a = red[0][j2][l2], b = red[1][j2][l2];
  const float4 c = red[2][j2][l2], d = red[3][j2][l2];
  float4 o;
  o.x = fmaxf(fmaxf(a.x, b.x), fmaxf(c.x, d.x));
  o.y = fmaxf(fmaxf(a.y, b.y), fmaxf(c.y, d.y));
  o.z = fmaxf(fmaxf(a.z, b.z), fmaxf(c.z, d.z));
  o.w = fmaxf(fmaxf(a.w, b.w), fmaxf(c.w, d.w));
  *(float4*)&pmax[((size_t)e * 64 + hb) * 1024 + j2 * 256 + l2 * 4] = o;
}

// stage 2: fold 64 partials per column -> swc[e][colp] = amax/127
__global__ __launch_bounds__(256) void k_wamax_red(
    const float* __restrict__ pmax, float* __restrict__ swc) {
  const int flat = blockIdx.x * 256 + threadIdx.x;   // 9216
  const int e = flat >> 10, c = flat & 1023;
  float m = 0.f;
  for (int hb = 0; hb < 64; ++hb)
    m = fmaxf(m, pmax[((size_t)e * 64 + hb) * 1024 + c]);
  swc[e * 1024 + colp_of(c)] = m * (1.f / 127.f);
}

// ---------------- k_cvt_wgup: 128h x 64c tiles, 8-deep load ILP ----------------
// grid: 9 * 16(c) * 8(h) = 1152 blocks
__global__ __launch_bounds__(256) void k_cvt_wgup(
    const float* __restrict__ wgu, const float* __restrict__ wsg,
    const float* __restrict__ swc, i8* __restrict__ wguq) {
  __shared__ float tile[64][130];
  const int b = blockIdx.x, tid = threadIdx.x;
  const int e = b / 128, rem = b % 128;
  const int c0 = (rem & 15) * 64, h0 = (rem >> 4) * 128;
  const float* src = (e < 8) ? (wgu + (size_t)e * HID * 1024) : wsg;

  const int hl = tid >> 1, cb = (tid & 1) * 32;
  float4 v[8];
#pragma unroll
  for (int j = 0; j < 8; ++j)
    v[j] = *(const float4*)&src[(size_t)(h0 + hl) * 1024 + c0 + cb + j * 4];
#pragma unroll
  for (int j = 0; j < 8; ++j) {
    tile[cb + j * 4 + 0][hl] = v[j].x;
    tile[cb + j * 4 + 1][hl] = v[j].y;
    tile[cb + j * 4 + 2][hl] = v[j].z;
    tile[cb + j * 4 + 3][hl] = v[j].w;
  }
  __syncthreads();
  const int cl = tid >> 2, hb = (tid & 3) * 32;
  const int cp = colp_of(c0 + cl);
  const float inv = 1.f / swc[e * 1024 + cp];
  i8 out[32];
#pragma unroll
  for (int k = 0; k < 32; ++k) out[k] = (i8)q8(tile[cl][hb + k], inv);
  i8* dst = &wguq[((size_t)e * 1024 + cp) * 1024 + h0 + hb];
  *(int4*)dst = *(int4*)out;
  *(int4*)(dst + 16) = *(int4*)(out + 16);
}

// ---------------- k_cvt_wdn: 128i x 64h tiles -> bf16 [e][h][i] ----------------
// grid: 9 * 16(h) * 4(i) = 576 blocks
__global__ __launch_bounds__(256) void k_cvt_wdn(
    const float* __restrict__ wdn, const float* __restrict__ wsd,
    u16* __restrict__ wdT) {
  __shared__ float tile[64][130];
  const int b = blockIdx.x, tid = threadIdx.x;
  const int e = b / 64, rem = b % 64;
  const int h0 = (rem & 15) * 64, i0 = (rem >> 4) * 128;
  const float* src = (e < 8) ? (wdn + (size_t)e * ISZ * HID) : wsd;

  const int il = tid >> 1, hb = (tid & 1) * 32;
  float4 v[8];
#pragma unroll
  for (int j = 0; j < 8; ++j)
    v[j] = *(const float4*)&src[(size_t)(i0 + il) * 1024 + h0 + hb + j * 4];
#pragma unroll
  for (int j = 0; j < 8; ++j) {
    tile[hb + j * 4 + 0][il] = v[j].x;
    tile[hb + j * 4 + 1][il] = v[j].y;
    tile[hb + j * 4 + 2][il] = v[j].z;
    tile[hb + j * 4 + 3][il] = v[j].w;
  }
  __syncthreads();
  const int hl = tid >> 2, ib = (tid & 3) * 32;
  u16 ob[32];
#pragma unroll
  for (int k = 0; k < 32; ++k) ob[k] = f2bf(tile[hl][ib + k]);
  u16* dst = &wdT[((size_t)e * HID + h0 + hl) * ISZ + i0 + ib];
  *(int4*)dst        = *(int4*)ob;
  *(int4*)(dst + 8)  = *(int4*)(ob + 8);
  *(int4*)(dst + 16) = *(int4*)(ob + 16);
  *(int4*)(dst + 24) = *(int4*)(ob + 24);
}

// ---------------- k_router: top-2 + per-row x quant ----------------
__global__ __launch_bounds__(256) void k_router(
    const float* __restrict__ x, const float* __restrict__ wg,
    i8* __restrict__ xq, float* __restrict__ sxg,
    int* __restrict__ eidx, float2* __restrict__ wts) {
  const int t = blockIdx.x * 4 + (threadIdx.x >> 6);
  const int l = threadIdx.x & 63;
  float a[8] = {0, 0, 0, 0, 0, 0, 0, 0};
  float vals[16];
  float am = 0.f;
  const float4* xr4 = (const float4*)(x + (size_t)t * HID);
#pragma unroll
  for (int j = 0; j < 4; ++j) {
    const float4 v = xr4[j * 64 + l];
    vals[4 * j] = v.x; vals[4 * j + 1] = v.y; vals[4 * j + 2] = v.z; vals[4 * j + 3] = v.w;
    am = fmaxf(am, fmaxf(fmaxf(fabsf(v.x), fabsf(v.y)), fmaxf(fabsf(v.z), fabsf(v.w))));
    const int h = (j * 64 + l) * 4;
#pragma unroll
    for (int i = 0; i < 4; ++i) {
      const float4 w0 = *(const float4*)&wg[(h + i) * 8];
      const float4 w1 = *(const float4*)&wg[(h + i) * 8 + 4];
      const float ev = vals[4 * j + i];
      a[0] += ev * w0.x; a[1] += ev * w0.y; a[2] += ev * w0.z; a[3] += ev * w0.w;
      a[4] += ev * w1.x; a[5] += ev * w1.y; a[6] += ev * w1.z; a[7] += ev * w1.w;
    }
  }
#pragma unroll
  for (int off = 32; off >= 1; off >>= 1) {
    am = fmaxf(am, __shfl_xor(am, off));
#pragma unroll
    for (int e2 = 0; e2 < 8; ++e2) a[e2] += __shfl_xor(a[e2], off);
  }
  const float inv = (am > 0.f) ? 127.f / am : 0.f;
  u32* xq4 = (u32*)(xq + (size_t)t * HID);
#pragma unroll
  for (int j = 0; j < 4; ++j) {
    u32 q = ((u32)(unsigned char)(i8)q8(vals[4 * j], inv)) |
            ((u32)(unsigned char)(i8)q8(vals[4 * j + 1], inv) << 8) |
            ((u32)(unsigned char)(i8)q8(vals[4 * j + 2], inv) << 16) |
            ((u32)(unsigned char)(i8)q8(vals[4 * j + 3], inv) << 24);
    xq4[j * 64 + l] = q;
  }
  if (l == 0) {
    sxg[t] = am * (1.f / 127.f);
    int ia = 0;
#pragma unroll
    for (int e2 = 1; e2 < 8; ++e2) if (a[e2] > a[ia]) ia = e2;
    int ib = (ia == 0) ? 1 : 0;
#pragma unroll
    for (int e2 = 0; e2 < 8; ++e2) if (e2 != ia && a[e2] > a[ib]) ib = e2;
    float wa = 1.f / (1.f + expf(a[ib] - a[ia]));
    eidx[t] = ia | (ib << 8);
    wts[t] = make_float2(wa, 1.f - wa);
  }
}

// ---------------- deterministic counting scatter (256-aligned segments) --------
__global__ __launch_bounds__(512) void k_scatter(
    const int* __restrict__ eidx, int* __restrict__ btok, int* __restrict__ slotmap,
    int* __restrict__ seg, int* __restrict__ segcnt) {
  __shared__ int cnt_s[8];
  __shared__ int goff_s[9];
  const int e = threadIdx.x >> 6;
  const int l = threadIdx.x & 63;

  int c1 = 0;
  for (int c = 0; c < T_TOK / 64; ++c) {
    int v = eidx[c * 64 + l];
    c1 += __popcll(__ballot((v & 255) == e)) + __popcll(__ballot(((v >> 8) & 255) == e));
  }
  if (l == 0) cnt_s[e] = c1;
  __syncthreads();
  if (threadIdx.x == 0) {
    int off = 0;
    for (int k = 0; k < 8; ++k) { goff_s[k] = off; off += (cnt_s[k] + 255) & ~255; }
    goff_s[8] = off;
  }
  __syncthreads();
  const int base0 = goff_s[e];
  const int cnt_e = cnt_s[e];
  const unsigned long long below = (l == 63) ? ~0ull >> 1 : ((1ull << l) - 1);

  int base = base0;
  for (int c = 0; c < T_TOK / 64; ++c) {
    const int t = c * 64 + l;
    const int v = eidx[t];
    const unsigned long long ma = __ballot((v & 255) == e);
    const unsigned long long mb = __ballot(((v >> 8) & 255) == e);
    if ((v & 255) == e) {
      int s = base + __popcll(ma & below);
      btok[s] = t; slotmap[2 * t] = s;
    }
    if (((v >> 8) & 255) == e) {
      int s = base + __popcll(ma) + __popcll(mb & below);
      btok[s] = t; slotmap[2 * t + 1] = s;
    }
    base += __popcll(ma) + __popcll(mb);
  }
  for (int p = cnt_e + l; p < ((cnt_e + 255) & ~255); p += 64) btok[base0 + p] = 0;
  if (threadIdx.x < 9) seg[threadIdx.x] = goff_s[threadIdx.x];
  if (threadIdx.x < 8) segcnt[threadIdx.x] = cnt_s[threadIdx.x];
}

__device__ __forceinline__ bool seg_lookup(const int* __restrict__ seg,
                                           const int* __restrict__ segcnt,
                                           int brow, int& e) {
  if (brow >= RBASE) { e = 8; return true; }
  if (brow >= seg[8]) return false;
  e = 0;
#pragma unroll
  for (int k = 1; k < 8; ++k) if (brow >= seg[k]) e = k;
  return brow < seg[e] + segcnt[e];
}

// =================================================================================
// GEMM1 (int8): 256x128 tile, K-slot=128 i8, 8 waves 4M x 2N (64x64), 3-ring LDS,
// counted vmcnt(6)/lgkm(8), ^(row&7) swizzle (0 conflicts). Per-column dequant.
// =================================================================================

#define G1_STG(kt) do {                                             \
    const int _ra = ((kt) % 3) * 32768;                             \
    STAGE(sA0 + (kt) * 128, Ab + _ra + 0 * 8192 + w * 1024);        \
    STAGE(sA1 + (kt) * 128, Ab + _ra + 1 * 8192 + w * 1024);        \
    STAGE(sA2 + (kt) * 128, Ab + _ra + 2 * 8192 + w * 1024);        \
    STAGE(sA3 + (kt) * 128, Ab + _ra + 3 * 8192 + w * 1024);        \
    const int _rb = ((kt) % 3) * 16384;                             \
    STAGE(sB0 + (kt) * 128, Bb + _rb + 0 * 8192 + w * 1024);        \
    STAGE(sB1 + (kt) * 128, Bb + _rb + 1 * 8192 + w * 1024); } while (0)

#define G1_LOADF(SA, SB, RG, KX) do {                               \
    _Pragma("unroll") for (int m = 0; m < 4; ++m)                   \
      SA[m] = *(const i32x4*)&Ab[(RG) * 32768 + aBase + m * 2048 + (KX)]; \
    _Pragma("unroll") for (int n = 0; n < 4; ++n)                   \
      SB[n] = *(const i32x4*)&Bb[(RG) * 16384 + bBase + n * 2048 + (KX)]; } while (0)

#define G1_MFMA(SA, SB) do { __builtin_amdgcn_s_setprio(1);         \
    _Pragma("unroll") for (int m = 0; m < 4; ++m)                   \
      _Pragma("unroll") for (int n = 0; n < 4; ++n)                 \
        acc[m][n] = __builtin_amdgcn_mfma_i32_16x16x64_i8(SA[m], SB[n], acc[m][n], 0, 0, 0); \
    __builtin_amdgcn_s_setprio(0); } while (0)

__global__ __launch_bounds__(512) void k_gemm_gu(
    const i8* __restrict__ xq,      // [T][1024] i8
    const i8* __restrict__ wguq,    // [NE][1024][1024] i8 (B^T, gate/up interleaved)
    const int* __restrict__ seg, const int* __restrict__ segcnt,
    const int* __restrict__ btok, const float* __restrict__ sxg,
    const float* __restrict__ swc,  // [NE][1024] per-column scale (amax/127)
    u16* __restrict__ act)          // [NSLOT][ISZ] bf16
{
  const int bid = blockIdx.x;
  const int brow = (bid % NROWB) * BM;
  const int bcol = (bid / NROWB) * 128;
  int e;
  if (!seg_lookup(seg, segcnt, brow, e)) return;

  __shared__ __align__(16) i8 Ab[3 * 32768];   // 96 KB
  __shared__ __align__(16) i8 Bb[3 * 16384];   // 48 KB
  __shared__ float sxl[BM];
  __shared__ float swcl[128];

  const int tid = threadIdx.x;
  const int w = tid >> 6, l = tid & 63;
  const int wm = w >> 1, wn = w & 1;           // 4M x 2N
  const int fr = l & 15, fg = l >> 4;

  if (tid < BM) {
    const int rrow = brow + tid;
    const int tk = (e < 8) ? btok[rrow] : (rrow - RBASE);
    sxl[tid] = sxg[tk];
  }
  if (tid >= BM && tid < BM + 128) swcl[tid - BM] = swc[e * 1024 + bcol + (tid - BM)];

  const int rr = w * 8 + (l >> 3);
  const int sw = ((l & 7) ^ (l >> 3)) * 16;
  int tr[4];
#pragma unroll
  for (int j = 0; j < 4; ++j) {
    const int gr = brow + j * 64 + rr;
    tr[j] = (e < 8) ? btok[gr] : (gr - RBASE);
  }
  const i8* sA0 = xq + (size_t)tr[0] * HID + sw;
  const i8* sA1 = xq + (size_t)tr[1] * HID + sw;
  const i8* sA2 = xq + (size_t)tr[2] * HID + sw;
  const i8* sA3 = xq + (size_t)tr[3] * HID + sw;
  const i8* sB0 = wguq + ((size_t)e * 1024 + bcol + 0 * 64 + rr) * HID + sw;
  const i8* sB1 = wguq + ((size_t)e * 1024 + bcol + 1 * 64 + rr) * HID + sw;

  const int aBase = (wm * 64 + fr) * 128;
  const int bBase = (wn * 64 + fr) * 128;
  const int kx0 = (fg ^ (fr & 7)) * 16;
  const int kx1 = kx0 ^ 64;

  i32x4 acc[4][4];
#pragma unroll
  for (int m = 0; m < 4; ++m)
#pragma unroll
    for (int n = 0; n < 4; ++n) acc[m][n] = (i32x4){0, 0, 0, 0};
  i32x4 fA0[4], fB0[4], fA1[4], fB1[4];

  const int NKT = HID / 128;   // 8 slots
  G1_STG(0); G1_STG(1);
  asm volatile("s_waitcnt vmcnt(6)" ::: "memory");
  __builtin_amdgcn_s_barrier();
  for (int s = 0; s < NKT; ++s) {
    const int rg = s % 3;
    if (s + 2 < NKT) G1_STG(s + 2);
    G1_LOADF(fA0, fB0, rg, kx0);
    __builtin_amdgcn_sched_barrier(0);
    G1_LOADF(fA1, fB1, rg, kx1);
    asm volatile("s_waitcnt lgkmcnt(8)" ::: "memory");
    __builtin_amdgcn_sched_barrier(0);
    G1_MFMA(fA0, fB0);
    asm volatile("s_waitcnt lgkmcnt(0)" ::: "memory");
    __builtin_amdgcn_sched_barrier(0);
    G1_MFMA(fA1, fB1);
    if (s + 1 < NKT) {
      if (s + 2 < NKT) { asm volatile("s_waitcnt vmcnt(6)" ::: "memory"); }
      else             { asm volatile("s_waitcnt vmcnt(0)" ::: "memory"); }
      __builtin_amdgcn_s_barrier();
    }
  }

#pragma unroll
  for (int m = 0; m < 4; ++m) {
#pragma unroll
    for (int p = 0; p < 2; ++p) {
      const i32x4 gI = acc[m][2 * p], uI = acc[m][2 * p + 1];
      const int col = ((bcol + wn * 64) >> 1) + p * 16 + fr;
      const float swg = swcl[wn * 64 + p * 32 + fr];
      const float swu = swcl[wn * 64 + p * 32 + 16 + fr];
#pragma unroll
      for (int r = 0; r < 4; ++r) {
        const int row_l = wm * 64 + m * 16 + fg * 4 + r;
        const float sx = sxl[row_l];
        const float gate = (float)gI[r] * (sx * swg);
        const float up   = (float)uI[r] * (sx * swu);
        const float sv = gate / (1.f + __expf(-gate));
        act[(size_t)(brow + row_l) * ISZ + col] = f2bf(sv * up);
      }
    }
  }
}

// =================================================================================
// GEMM2 (bf16): 256x256 tile, BK=32, 8 waves 2M x 4N (128x64), 3-ring LDS,
// counted vmcnt(4), 2 phases / K-tile.
// =================================================================================

#define D_STGA(kt) do { const int _d = ((kt) % 3) * 8192 + w * 1024; \
    STAGE(dA0 + (kt) * 32, As + _d);                                 \
    STAGE(dA1 + (kt) * 32, As + _d + 512); } while (0)
#define D_STGB(kt) do { const int _d = ((kt) % 3) * 8192 + w * 1024; \
    STAGE(dB0 + (kt) * 32, Bs + _d);                                 \
    STAGE(dB1 + (kt) * 32, Bs + _d + 512); } while (0)
#define D_LDA4(sl, mb) do {                                          \
    af[0] = *(const short8*)&As[(sl) + aOff + ((mb) + 0) * 512];     \
    af[1] = *(const short8*)&As[(sl) + aOff + ((mb) + 1) * 512];     \
    af[2] = *(const short8*)&As[(sl) + aOff + ((mb) + 2) * 512];     \
    af[3] = *(const short8*)&As[(sl) + aOff + ((mb) + 3) * 512]; } while (0)
#define D_LDB4(sl) do {                                              \
    bf[0] = *(const short8*)&Bs[(sl) + bOff + 0 * 512];              \
    bf[1] = *(const short8*)&Bs[(sl) + bOff + 1 * 512];              \
    bf[2] = *(const short8*)&Bs[(sl) + bOff + 2 * 512];              \
    bf[3] = *(const short8*)&Bs[(sl) + bOff + 3 * 512]; } while (0)
#define D_MFMA16(mb) do { __builtin_amdgcn_s_setprio(1);             \
    _Pragma("unroll") for (int mm = 0; mm < 4; ++mm)                 \
      _Pragma("unroll") for (int nn = 0; nn < 4; ++nn)               \
        accf[(mb) + mm][nn] = __builtin_amdgcn_mfma_f32_16x16x32_bf16( \
            af[mm], bf[nn], accf[(mb) + mm][nn], 0, 0, 0);           \
    __builtin_amdgcn_s_setprio(0); } while (0)

__global__ __launch_bounds__(512) void k_gemm_down(
    const u16* __restrict__ act, const u16* __restrict__ wdT,
    const int* __restrict__ seg, const int* __restrict__ segcnt,
    u16* __restrict__ tmp) {
  const int brow = blockIdx.x * BM;
  const int bcol = blockIdx.y * 256;
  int e;
  if (!seg_lookup(seg, segcnt, brow, e)) return;

  __shared__ __align__(16) u16 As[3 * 8192];
  __shared__ __align__(16) u16 Bs[3 * 8192];

  const int tid = threadIdx.x;
  const int w = tid >> 6, l = tid & 63;
  const int wm = w >> 2, wn = w & 3;
  const int fr = l & 15, fg = l >> 4;

  const int arow0 = (w * 128 + l) >> 2;
  const int swd = ((l & 3) ^ (arow0 & 3)) * 8;
  const u16* dA0 = act + (size_t)(brow + arow0) * ISZ + swd;
  const u16* dA1 = act + (size_t)(brow + arow0 + 16) * ISZ + swd;
  const u16* dB0 = wdT + ((size_t)e * 1024 + bcol + arow0) * ISZ + swd;
  const u16* dB1 = wdT + ((size_t)e * 1024 + bcol + arow0 + 16) * ISZ + swd;

  const int aOff = (wm * 128 + fr) * 32 + ((fg ^ (fr & 3)) * 8);
  const int bOff = (wn * 64 + fr) * 32 + ((fg ^ (fr & 3)) * 8);

  f32x4 accf[8][4];
#pragma unroll
  for (int m = 0; m < 8; ++m)
#pragma unroll
    for (int n = 0; n < 4; ++n) accf[m][n] = (f32x4){0.f, 0.f, 0.f, 0.f};
  short8 af[4], bf[4];

  const int NKT = ISZ / 32;   // 16
  D_STGA(0); D_STGB(0); D_STGA(1); D_STGB(1);
  asm volatile("s_waitcnt vmcnt(4)" ::: "memory");
  __builtin_amdgcn_s_barrier();
  for (int kt = 0; kt < NKT; ++kt) {
    const int sl = (kt % 3) * 8192;
    D_LDA4(sl, 0); D_LDB4(sl);
    if (kt + 2 < NKT) D_STGA(kt + 2);
    __builtin_amdgcn_s_barrier();
    asm volatile("s_waitcnt lgkmcnt(0)" ::: "memory");
    __builtin_amdgcn_sched_barrier(0);
    D_MFMA16(0);
    __builtin_amdgcn_s_barrier();
    D_LDA4(sl, 4);
    if (kt + 2 < NKT) D_STGB(kt + 2);
    __builtin_amdgcn_s_barrier();
    asm volatile("s_waitcnt lgkmcnt(0)" ::: "memory");
    __builtin_amdgcn_sched_barrier(0);
    D_MFMA16(4);
    if (kt + 2 < NKT)      { asm volatile("s_waitcnt vmcnt(4)" ::: "memory"); }
    else if (kt + 1 < NKT) { asm volatile("s_waitcnt vmcnt(0)" ::: "memory"); }
    __builtin_amdgcn_s_barrier();
  }

#pragma unroll
  for (int m = 0; m < 8; ++m) {
#pragma unroll
    for (int r = 0; r < 4; ++r) {
      const int row = brow + wm * 128 + m * 16 + fg * 4 + r;
#pragma unroll
      for (int n = 0; n < 4; ++n) {
        const int col = bcol + wn * 64 + n * 16 + fr;
        tmp[(size_t)row * HID + col] = f2bf(accf[m][n][r]);
      }
    }
  }
}

// ---------------- combine: out[t] = tmp[sh] + w0*tmp[s0] + w1*tmp[s1] -----------
__global__ __launch_bounds__(256) void k_combine(
    const u16* __restrict__ tmp, const int* __restrict__ slotmap,
    const float2* __restrict__ wts, float* __restrict__ out) {
  const int idx = blockIdx.x * 256 + threadIdx.x;
  const int t = idx >> 7;
  const int c = (idx & 127) << 3;
  const int s0 = slotmap[2 * t], s1 = slotmap[2 * t + 1];
  const float2 wv = wts[t];
  const short8 a = *(const short8*)(tmp + (size_t)s0 * HID + c);
  const short8 b = *(const short8*)(tmp + (size_t)s1 * HID + c);
  const short8 s = *(const short8*)(tmp + (size_t)(RBASE + t) * HID + c);
  float r[8];
#pragma unroll
  for (int j = 0; j < 8; ++j)
    r[j] = bf2f((u16)s[j]) + wv.x * bf2f((u16)a[j]) + wv.y * bf2f((u16)b[j]);
  float* po = out + (size_t)t * HID + c;
  *(float4*)po       = make_float4(r[0], r[1], r[2], r[3]);
  *(float4*)(po + 4) = make_float4(r[4], r[5], r[6], r[7]);
}

// ---------------- launch ----------------
extern "C" void kernel_launch(void* const* d_in, const int* in_sizes, int n_in,
                              void* d_out, int out_size, void* d_ws, size_t ws_size,
                              hipStream_t stream) {
  const float* x   = (const float*)d_in[0];
  const float* wg  = (const float*)d_in[1];
  const float* wgu = (const float*)d_in[2];
  const float* wdn = (const float*)d_in[3];
  const float* wsg = (const float*)d_in[4];
  const float* wsd = (const float*)d_in[5];
  float* out = (float*)d_out;

  char* ws = (char*)d_ws;
  i8*  xq    = (i8*)ws;   ws += (size_t)T_TOK * HID;
  i8*  wguq  = (i8*)ws;   ws += (size_t)NE * 1024 * HID;
  u16* wdT   = (u16*)ws;  ws += (size_t)NE * HID * ISZ * 2;
  u16* actb  = (u16*)ws;  ws += (size_t)NSLOT * ISZ * 2;
  u16* tmp   = (u16*)ws;  ws += (size_t)NSLOT * HID * 2;
  float* sxg = (float*)ws; ws += (size_t)T_TOK * 4;
  float* swc = (float*)ws; ws += (size_t)NE * 1024 * 4;
  float* pmx = (float*)ws; ws += (size_t)NE * 64 * 1024 * 4;
  int* eidx  = (int*)ws;  ws += (size_t)T_TOK * 4;
  float2* wt = (float2*)ws; ws += (size_t)T_TOK * 8;
  int* btok  = (int*)ws;  ws += (size_t)RBASE * 4;
  int* smap  = (int*)ws;  ws += (size_t)2 * T_TOK * 4;
  int* seg   = (int*)ws;  ws += 16 * 4;
  int* segc  = (int*)ws;

  k_wamax_part<<<dim3(64, NE), 256, 0, stream>>>(wgu, wsg, pmx);
  k_wamax_red<<<(NE * 1024) / 256, 256, 0, stream>>>(pmx, swc);
  k_cvt_wgup<<<128 * NE, 256, 0, stream>>>(wgu, wsg, swc, wguq);
  k_cvt_wdn<<<64 * NE, 256, 0, stream>>>(wdn, wsd, wdT);
  k_router<<<T_TOK / 4, 256, 0, stream>>>(x, wg, xq, sxg, eidx, wt);
  k_scatter<<<1, 512, 0, stream>>>(eidx, btok, smap, seg, segc);
  k_gemm_gu<<<NROWB * 8, 512, 0, stream>>>(
      xq, wguq, seg, segc, btok, sxg, swc, actb);
  k_gemm_down<<<dim3(NROWB, HID / 256), 512, 0, stream>>>(actb, wdT, seg, segc, tmp);
  k_combine<<<(T_TOK * HID / 8) / 256, 256, 0, stream>>>(tmp, smap, wt, out);
}

// Round 16
// 206.344 us; speedup vs baseline: 1.0766x; 1.0766x over previous
//
#include <hip/hip_runtime.h>
#include <hip/hip_bf16.h>
#include <cstdint>

#define T_TOK 8192
#define HID   1024
#define NE    9
#define ISZ   512
#define RBASE 18432
#define NSLOT (RBASE + T_TOK)   // 26624

#define BM 256
#define NROWB (NSLOT / BM)      // 104

typedef unsigned short u16;
typedef unsigned int   u32;
typedef signed char    i8;
typedef __attribute__((ext_vector_type(8))) short short8;
typedef __attribute__((ext_vector_type(4))) float f32x4;
typedef __attribute__((ext_vector_type(4))) int   i32x4;

__device__ __forceinline__ u16 f2bf(float f) {
  u32 u = __builtin_bit_cast(u32, f);
  return (u16)((u + 0x7fffu + ((u >> 16) & 1u)) >> 16);
}
__device__ __forceinline__ float bf2f(u16 v) {
  return __builtin_bit_cast(float, (u32)v << 16);
}
__device__ __forceinline__ int q8(float v, float inv) {
  int q = (int)__builtin_rintf(v * inv);
  return (q > 127) ? 127 : ((q < -127) ? -127 : q);
}
__device__ __forceinline__ int colp_of(int c) {
  int i = (c < 512) ? c : (c - 512);
  return (i >> 4) * 32 + ((c < 512) ? 0 : 16) + (i & 15);
}

#define STAGE(gp, lp) __builtin_amdgcn_global_load_lds( \
    (__attribute__((address_space(1))) u32*)(gp),       \
    (__attribute__((address_space(3))) u32*)(lp), 16, 0, 0)

// ---------------- per-column weight amax, stage 1: coalesced partials ----------
__global__ __launch_bounds__(256) void k_wamax_part(
    const float* __restrict__ wgu, const float* __restrict__ wsg,
    float* __restrict__ pmax) {
  const int e = blockIdx.y, hb = blockIdx.x;
  const float* src = (e < 8) ? (wgu + (size_t)e * 1048576) : wsg;
  const int wv = threadIdx.x >> 6, l = threadIdx.x & 63;
  float4 m4[4];
#pragma unroll
  for (int j = 0; j < 4; ++j) m4[j] = make_float4(0.f, 0.f, 0.f, 0.f);
  const int r0 = hb * 16 + wv * 4;
#pragma unroll
  for (int r = 0; r < 4; ++r) {
    const float* row = src + (size_t)(r0 + r) * 1024;
#pragma unroll
    for (int j = 0; j < 4; ++j) {
      const float4 v = *(const float4*)&row[j * 256 + l * 4];
      m4[j].x = fmaxf(m4[j].x, fabsf(v.x));
      m4[j].y = fmaxf(m4[j].y, fabsf(v.y));
      m4[j].z = fmaxf(m4[j].z, fabsf(v.z));
      m4[j].w = fmaxf(m4[j].w, fabsf(v.w));
    }
  }
  __shared__ float4 red[4][4][64];
#pragma unroll
  for (int j = 0; j < 4; ++j) red[wv][j][l] = m4[j];
  __syncthreads();
  const int j2 = threadIdx.x >> 6, l2 = threadIdx.x & 63;
  const float4 a = red[0][j2][l2], b = red[1][j2][l2];
  const float4 c = red[2][j2][l2], d = red[3][j2][l2];
  float4 o;
  o.x = fmaxf(fmaxf(a.x, b.x), fmaxf(c.x, d.x));
  o.y = fmaxf(fmaxf(a.y, b.y), fmaxf(c.y, d.y));
  o.z = fmaxf(fmaxf(a.z, b.z), fmaxf(c.z, d.z));
  o.w = fmaxf(fmaxf(a.w, b.w), fmaxf(c.w, d.w));
  *(float4*)&pmax[((size_t)e * 64 + hb) * 1024 + j2 * 256 + l2 * 4] = o;
}

__global__ __launch_bounds__(256) void k_wamax_red(
    const float* __restrict__ pmax, float* __restrict__ swc) {
  const int flat = blockIdx.x * 256 + threadIdx.x;   // 9216
  const int e = flat >> 10, c = flat & 1023;
  float m = 0.f;
  for (int hb = 0; hb < 64; ++hb)
    m = fmaxf(m, pmax[((size_t)e * 64 + hb) * 1024 + c]);
  swc[e * 1024 + colp_of(c)] = m * (1.f / 127.f);
}

// ---------------- k_prep (r14 fused version): transposes + router ----------------
#define NB_WGUP (32 * 8 * NE)    // 2304
#define NB_WDN  (32 * 4 * NE)    // 1152
#define NB_RTR  (T_TOK / 4)      // 2048

__global__ __launch_bounds__(256) void k_prep(
    const float* __restrict__ x, const float* __restrict__ wg,
    const float* __restrict__ wgu, const float* __restrict__ wsg,
    const float* __restrict__ wdn, const float* __restrict__ wsd,
    const float* __restrict__ swc,
    i8* __restrict__ xq, float* __restrict__ sxg,
    i8* __restrict__ wguq, u16* __restrict__ wdT,
    int* __restrict__ eidx, float2* __restrict__ wts) {
  __shared__ float tile[32][129];
  const int b = blockIdx.x;
  const int tid = threadIdx.x;

  if (b < NB_WGUP) {
    const int e = b / 256, rem = b % 256;
    const int c0 = (rem & 31) * 32, h0 = (rem >> 5) * 128;
    const float* src = (e < 8) ? (wgu + (size_t)e * HID * 1024) : wsg;
    const int hl = tid >> 1, cb = (tid & 1) * 16;
#pragma unroll
    for (int j = 0; j < 4; ++j) {
      const float4 v = *(const float4*)&src[(size_t)(h0 + hl) * 1024 + c0 + cb + j * 4];
      tile[cb + j * 4 + 0][hl] = v.x;
      tile[cb + j * 4 + 1][hl] = v.y;
      tile[cb + j * 4 + 2][hl] = v.z;
      tile[cb + j * 4 + 3][hl] = v.w;
    }
    __syncthreads();
    const int cl = tid >> 3, hb = (tid & 7) * 16;
    const int cp = colp_of(c0 + cl);
    const float inv = 1.f / swc[e * 1024 + cp];
    i8 out[16];
#pragma unroll
    for (int k = 0; k < 16; ++k) out[k] = (i8)q8(tile[cl][hb + k], inv);
    *(int4*)&wguq[((size_t)e * 1024 + cp) * 1024 + h0 + hb] = *(int4*)out;
    return;
  }
  if (b < NB_WGUP + NB_WDN) {
    const int bb = b - NB_WGUP;
    const int e = bb / 128, r2 = bb % 128;
    const int h0 = (r2 & 31) * 32, i0 = (r2 >> 5) * 128;
    const float* src = (e < 8) ? (wdn + (size_t)e * ISZ * HID) : wsd;
    const int il = tid >> 1, hb2 = (tid & 1) * 16;
#pragma unroll
    for (int j = 0; j < 4; ++j) {
      const float4 v = *(const float4*)&src[(size_t)(i0 + il) * 1024 + h0 + hb2 + j * 4];
      tile[hb2 + j * 4 + 0][il] = v.x;
      tile[hb2 + j * 4 + 1][il] = v.y;
      tile[hb2 + j * 4 + 2][il] = v.z;
      tile[hb2 + j * 4 + 3][il] = v.w;
    }
    __syncthreads();
    const int hl2 = tid >> 3, ib = (tid & 7) * 16;
    u16 ob[16];
#pragma unroll
    for (int k = 0; k < 16; ++k) ob[k] = f2bf(tile[hl2][ib + k]);
    u16* dst = &wdT[((size_t)e * HID + h0 + hl2) * ISZ + i0 + ib];
    *(int4*)dst = *(int4*)ob;
    *(int4*)(dst + 8) = *(int4*)(ob + 8);
    return;
  }
  const int t = (b - NB_WGUP - NB_WDN) * 4 + (tid >> 6);
  const int l = tid & 63;
  float a[8] = {0, 0, 0, 0, 0, 0, 0, 0};
  float vals[16];
  float am = 0.f;
  const float4* xr4 = (const float4*)(x + (size_t)t * HID);
#pragma unroll
  for (int j = 0; j < 4; ++j) {
    const float4 v = xr4[j * 64 + l];
    vals[4 * j] = v.x; vals[4 * j + 1] = v.y; vals[4 * j + 2] = v.z; vals[4 * j + 3] = v.w;
    am = fmaxf(am, fmaxf(fmaxf(fabsf(v.x), fabsf(v.y)), fmaxf(fabsf(v.z), fabsf(v.w))));
    const int h = (j * 64 + l) * 4;
#pragma unroll
    for (int i = 0; i < 4; ++i) {
      const float4 w0 = *(const float4*)&wg[(h + i) * 8];
      const float4 w1 = *(const float4*)&wg[(h + i) * 8 + 4];
      const float ev = vals[4 * j + i];
      a[0] += ev * w0.x; a[1] += ev * w0.y; a[2] += ev * w0.z; a[3] += ev * w0.w;
      a[4] += ev * w1.x; a[5] += ev * w1.y; a[6] += ev * w1.z; a[7] += ev * w1.w;
    }
  }
#pragma unroll
  for (int off = 32; off >= 1; off >>= 1) {
    am = fmaxf(am, __shfl_xor(am, off));
#pragma unroll
    for (int e2 = 0; e2 < 8; ++e2) a[e2] += __shfl_xor(a[e2], off);
  }
  const float inv = (am > 0.f) ? 127.f / am : 0.f;
  u32* xq4 = (u32*)(xq + (size_t)t * HID);
#pragma unroll
  for (int j = 0; j < 4; ++j) {
    u32 q = ((u32)(unsigned char)(i8)q8(vals[4 * j], inv)) |
            ((u32)(unsigned char)(i8)q8(vals[4 * j + 1], inv) << 8) |
            ((u32)(unsigned char)(i8)q8(vals[4 * j + 2], inv) << 16) |
            ((u32)(unsigned char)(i8)q8(vals[4 * j + 3], inv) << 24);
    xq4[j * 64 + l] = q;
  }
  if (l == 0) {
    sxg[t] = am * (1.f / 127.f);
    int ia = 0;
#pragma unroll
    for (int e2 = 1; e2 < 8; ++e2) if (a[e2] > a[ia]) ia = e2;
    int ib = (ia == 0) ? 1 : 0;
#pragma unroll
    for (int e2 = 0; e2 < 8; ++e2) if (e2 != ia && a[e2] > a[ib]) ib = e2;
    float wa = 1.f / (1.f + expf(a[ib] - a[ia]));
    eidx[t] = ia | (ib << 8);
    wts[t] = make_float2(wa, 1.f - wa);
  }
}

// ---------------- deterministic counting scatter (256-aligned segments) --------
__global__ __launch_bounds__(512) void k_scatter(
    const int* __restrict__ eidx, int* __restrict__ btok, int* __restrict__ slotmap,
    int* __restrict__ seg, int* __restrict__ segcnt) {
  __shared__ int cnt_s[8];
  __shared__ int goff_s[9];
  const int e = threadIdx.x >> 6;
  const int l = threadIdx.x & 63;

  int c1 = 0;
  for (int c = 0; c < T_TOK / 64; ++c) {
    int v = eidx[c * 64 + l];
    c1 += __popcll(__ballot((v & 255) == e)) + __popcll(__ballot(((v >> 8) & 255) == e));
  }
  if (l == 0) cnt_s[e] = c1;
  __syncthreads();
  if (threadIdx.x == 0) {
    int off = 0;
    for (int k = 0; k < 8; ++k) { goff_s[k] = off; off += (cnt_s[k] + 255) & ~255; }
    goff_s[8] = off;
  }
  __syncthreads();
  const int base0 = goff_s[e];
  const int cnt_e = cnt_s[e];
  const unsigned long long below = (l == 63) ? ~0ull >> 1 : ((1ull << l) - 1);

  int base = base0;
  for (int c = 0; c < T_TOK / 64; ++c) {
    const int t = c * 64 + l;
    const int v = eidx[t];
    const unsigned long long ma = __ballot((v & 255) == e);
    const unsigned long long mb = __ballot(((v >> 8) & 255) == e);
    if ((v & 255) == e) {
      int s = base + __popcll(ma & below);
      btok[s] = t; slotmap[2 * t] = s;
    }
    if (((v >> 8) & 255) == e) {
      int s = base + __popcll(ma) + __popcll(mb & below);
      btok[s] = t; slotmap[2 * t + 1] = s;
    }
    base += __popcll(ma) + __popcll(mb);
  }
  for (int p = cnt_e + l; p < ((cnt_e + 255) & ~255); p += 64) btok[base0 + p] = 0;
  if (threadIdx.x < 9) seg[threadIdx.x] = goff_s[threadIdx.x];
  if (threadIdx.x < 8) segcnt[threadIdx.x] = cnt_s[threadIdx.x];
}

__device__ __forceinline__ bool seg_lookup(const int* __restrict__ seg,
                                           const int* __restrict__ segcnt,
                                           int brow, int& e) {
  if (brow >= RBASE) { e = 8; return true; }
  if (brow >= seg[8]) return false;
  e = 0;
#pragma unroll
  for (int k = 1; k < 8; ++k) if (brow >= seg[k]) e = k;
  return brow < seg[e] + segcnt[e];
}

// =================================================================================
// GEMM1 (int8): 256x256 tile, K-slot=128 i8, 8 waves 4M x 2N (per-wave 64x128).
// LDS: 2-ring A (2x32KB) + 2-ring B (2x32KB) = 128KB. Depth-1 stage-ahead:
// stage slot s+1 during s, end-of-slot vmcnt(0)+barrier (latency hides under
// 24 ds_reads + 64 MFMA per wave). ^(row&7) 16B-chunk swizzle (0 conflicts).
// A staged once per 2 col-blocks vs r15 -> total staged 319 -> 213 MB.
// =================================================================================

#define G1_STG(kt) do { const int _r = ((kt) & 1) * 32768;          \
    STAGE(sA0 + (kt) * 128, Ab + _r + 0 * 8192 + w * 1024);         \
    STAGE(sA1 + (kt) * 128, Ab + _r + 1 * 8192 + w * 1024);         \
    STAGE(sA2 + (kt) * 128, Ab + _r + 2 * 8192 + w * 1024);         \
    STAGE(sA3 + (kt) * 128, Ab + _r + 3 * 8192 + w * 1024);         \
    STAGE(sB0 + (kt) * 128, Bb + _r + 0 * 8192 + w * 1024);         \
    STAGE(sB1 + (kt) * 128, Bb + _r + 1 * 8192 + w * 1024);         \
    STAGE(sB2 + (kt) * 128, Bb + _r + 2 * 8192 + w * 1024);         \
    STAGE(sB3 + (kt) * 128, Bb + _r + 3 * 8192 + w * 1024); } while (0)

#define G1_LOADF(RG, KX) do {                                       \
    _Pragma("unroll") for (int m = 0; m < 4; ++m)                   \
      fA[m] = *(const i32x4*)&Ab[(RG) * 32768 + aBase + m * 2048 + (KX)]; \
    _Pragma("unroll") for (int n = 0; n < 8; ++n)                   \
      fB[n] = *(const i32x4*)&Bb[(RG) * 32768 + bBase + n * 2048 + (KX)]; } while (0)

#define G1_MFMA do { __builtin_amdgcn_s_setprio(1);                 \
    _Pragma("unroll") for (int m = 0; m < 4; ++m)                   \
      _Pragma("unroll") for (int n = 0; n < 8; ++n)                 \
        acc[m][n] = __builtin_amdgcn_mfma_i32_16x16x64_i8(fA[m], fB[n], acc[m][n], 0, 0, 0); \
    __builtin_amdgcn_s_setprio(0); } while (0)

__global__ __launch_bounds__(512) void k_gemm_gu(
    const i8* __restrict__ xq,      // [T][1024] i8
    const i8* __restrict__ wguq,    // [NE][1024][1024] i8 (B^T, gate/up interleaved)
    const int* __restrict__ seg, const int* __restrict__ segcnt,
    const int* __restrict__ btok, const float* __restrict__ sxg,
    const float* __restrict__ swc,  // [NE][1024] per-column scale (amax/127)
    u16* __restrict__ act)          // [NSLOT][ISZ] bf16
{
  const int bid = blockIdx.x;
  const int brow = (bid % NROWB) * BM;
  const int bcol = (bid / NROWB) * 256;
  int e;
  if (!seg_lookup(seg, segcnt, brow, e)) return;

  __shared__ __align__(16) i8 Ab[2 * 32768];   // 64 KB
  __shared__ __align__(16) i8 Bb[2 * 32768];   // 64 KB
  __shared__ float sxl[BM];
  __shared__ float swcl[256];

  const int tid = threadIdx.x;
  const int w = tid >> 6, l = tid & 63;
  const int wm = w >> 1, wn = w & 1;           // 4M x 2N -> 64x128 per wave
  const int fr = l & 15, fg = l >> 4;

  if (tid < BM) {
    const int rrow = brow + tid;
    const int tk = (e < 8) ? btok[rrow] : (rrow - RBASE);
    sxl[tid] = sxg[tk];
  } else {
    swcl[tid - 256] = swc[e * 1024 + bcol + (tid - 256)];
  }

  const int rr = w * 8 + (l >> 3);
  const int sw = ((l & 7) ^ (l >> 3)) * 16;
  int tr[4];
#pragma unroll
  for (int j = 0; j < 4; ++j) {
    const int gr = brow + j * 64 + rr;
    tr[j] = (e < 8) ? btok[gr] : (gr - RBASE);
  }
  const i8* sA0 = xq + (size_t)tr[0] * HID + sw;
  const i8* sA1 = xq + (size_t)tr[1] * HID + sw;
  const i8* sA2 = xq + (size_t)tr[2] * HID + sw;
  const i8* sA3 = xq + (size_t)tr[3] * HID + sw;
  const i8* sB0 = wguq + ((size_t)e * 1024 + bcol + 0 * 64 + rr) * HID + sw;
  const i8* sB1 = wguq + ((size_t)e * 1024 + bcol + 1 * 64 + rr) * HID + sw;
  const i8* sB2 = wguq + ((size_t)e * 1024 + bcol + 2 * 64 + rr) * HID + sw;
  const i8* sB3 = wguq + ((size_t)e * 1024 + bcol + 3 * 64 + rr) * HID + sw;

  const int aBase = (wm * 64 + fr) * 128;
  const int bBase = (wn * 128 + fr) * 128;
  const int kx0 = (fg ^ (fr & 7)) * 16;
  const int kx1 = kx0 ^ 64;

  i32x4 acc[4][8];
#pragma unroll
  for (int m = 0; m < 4; ++m)
#pragma unroll
    for (int n = 0; n < 8; ++n) acc[m][n] = (i32x4){0, 0, 0, 0};
  i32x4 fA[4], fB[8];

  const int NKT = HID / 128;   // 8 slots
  G1_STG(0);
  asm volatile("s_waitcnt vmcnt(0)" ::: "memory");
  __builtin_amdgcn_s_barrier();
  for (int s = 0; s < NKT; ++s) {
    const int rg = s & 1;
    if (s + 1 < NKT) G1_STG(s + 1);
    G1_LOADF(rg, kx0);
    asm volatile("s_waitcnt lgkmcnt(0)" ::: "memory");
    __builtin_amdgcn_sched_barrier(0);
    G1_MFMA;
    G1_LOADF(rg, kx1);
    asm volatile("s_waitcnt lgkmcnt(0)" ::: "memory");
    __builtin_amdgcn_sched_barrier(0);
    G1_MFMA;
    asm volatile("s_waitcnt vmcnt(0)" ::: "memory");
    __builtin_amdgcn_s_barrier();
  }

#pragma unroll
  for (int m = 0; m < 4; ++m) {
#pragma unroll
    for (int p = 0; p < 4; ++p) {
      const i32x4 gI = acc[m][2 * p], uI = acc[m][2 * p + 1];
      const int col = ((bcol + wn * 128) >> 1) + p * 16 + fr;
      const float swg = swcl[wn * 128 + p * 32 + fr];
      const float swu = swcl[wn * 128 + p * 32 + 16 + fr];
#pragma unroll
      for (int r = 0; r < 4; ++r) {
        const int row_l = wm * 64 + m * 16 + fg * 4 + r;
        const float sx = sxl[row_l];
        const float gate = (float)gI[r] * (sx * swg);
        const float up   = (float)uI[r] * (sx * swu);
        const float sv = gate / (1.f + __expf(-gate));
        act[(size_t)(brow + row_l) * ISZ + col] = f2bf(sv * up);
      }
    }
  }
}

// =================================================================================
// GEMM2 (bf16): 256x256 tile, BK=32, 8 waves 2M x 4N (128x64), 3-ring LDS,
// counted vmcnt(4), 2 phases / K-tile.
// =================================================================================

#define D_STGA(kt) do { const int _d = ((kt) % 3) * 8192 + w * 1024; \
    STAGE(dA0 + (kt) * 32, As + _d);                                 \
    STAGE(dA1 + (kt) * 32, As + _d + 512); } while (0)
#define D_STGB(kt) do { const int _d = ((kt) % 3) * 8192 + w * 1024; \
    STAGE(dB0 + (kt) * 32, Bs + _d);                                 \
    STAGE(dB1 + (kt) * 32, Bs + _d + 512); } while (0)
#define D_LDA4(sl, mb) do {                                          \
    af[0] = *(const short8*)&As[(sl) + aOff + ((mb) + 0) * 512];     \
    af[1] = *(const short8*)&As[(sl) + aOff + ((mb) + 1) * 512];     \
    af[2] = *(const short8*)&As[(sl) + aOff + ((mb) + 2) * 512];     \
    af[3] = *(const short8*)&As[(sl) + aOff + ((mb) + 3) * 512]; } while (0)
#define D_LDB4(sl) do {                                              \
    bf[0] = *(const short8*)&Bs[(sl) + bOff + 0 * 512];              \
    bf[1] = *(const short8*)&Bs[(sl) + bOff + 1 * 512];              \
    bf[2] = *(const short8*)&Bs[(sl) + bOff + 2 * 512];              \
    bf[3] = *(const short8*)&Bs[(sl) + bOff + 3 * 512]; } while (0)
#define D_MFMA16(mb) do { __builtin_amdgcn_s_setprio(1);             \
    _Pragma("unroll") for (int mm = 0; mm < 4; ++mm)                 \
      _Pragma("unroll") for (int nn = 0; nn < 4; ++nn)               \
        accf[(mb) + mm][nn] = __builtin_amdgcn_mfma_f32_16x16x32_bf16( \
            af[mm], bf[nn], accf[(mb) + mm][nn], 0, 0, 0);           \
    __builtin_amdgcn_s_setprio(0); } while (0)

__global__ __launch_bounds__(512) void k_gemm_down(
    const u16* __restrict__ act, const u16* __restrict__ wdT,
    const int* __restrict__ seg, const int* __restrict__ segcnt,
    u16* __restrict__ tmp) {
  const int brow = blockIdx.x * BM;
  const int bcol = blockIdx.y * 256;
  int e;
  if (!seg_lookup(seg, segcnt, brow, e)) return;

  __shared__ __align__(16) u16 As[3 * 8192];
  __shared__ __align__(16) u16 Bs[3 * 8192];

  const int tid = threadIdx.x;
  const int w = tid >> 6, l = tid & 63;
  const int wm = w >> 2, wn = w & 3;
  const int fr = l & 15, fg = l >> 4;

  const int arow0 = (w * 128 + l) >> 2;
  const int swd = ((l & 3) ^ (arow0 & 3)) * 8;
  const u16* dA0 = act + (size_t)(brow + arow0) * ISZ + swd;
  const u16* dA1 = act + (size_t)(brow + arow0 + 16) * ISZ + swd;
  const u16* dB0 = wdT + ((size_t)e * 1024 + bcol + arow0) * ISZ + swd;
  const u16* dB1 = wdT + ((size_t)e * 1024 + bcol + arow0 + 16) * ISZ + swd;

  const int aOff = (wm * 128 + fr) * 32 + ((fg ^ (fr & 3)) * 8);
  const int bOff = (wn * 64 + fr) * 32 + ((fg ^ (fr & 3)) * 8);

  f32x4 accf[8][4];
#pragma unroll
  for (int m = 0; m < 8; ++m)
#pragma unroll
    for (int n = 0; n < 4; ++n) accf[m][n] = (f32x4){0.f, 0.f, 0.f, 0.f};
  short8 af[4], bf[4];

  const int NKT = ISZ / 32;   // 16
  D_STGA(0); D_STGB(0); D_STGA(1); D_STGB(1);
  asm volatile("s_waitcnt vmcnt(4)" ::: "memory");
  __builtin_amdgcn_s_barrier();
  for (int kt = 0; kt < NKT; ++kt) {
    const int sl = (kt % 3) * 8192;
    D_LDA4(sl, 0); D_LDB4(sl);
    if (kt + 2 < NKT) D_STGA(kt + 2);
    __builtin_amdgcn_s_barrier();
    asm volatile("s_waitcnt lgkmcnt(0)" ::: "memory");
    __builtin_amdgcn_sched_barrier(0);
    D_MFMA16(0);
    __builtin_amdgcn_s_barrier();
    D_LDA4(sl, 4);
    if (kt + 2 < NKT) D_STGB(kt + 2);
    __builtin_amdgcn_s_barrier();
    asm volatile("s_waitcnt lgkmcnt(0)" ::: "memory");
    __builtin_amdgcn_sched_barrier(0);
    D_MFMA16(4);
    if (kt + 2 < NKT)      { asm volatile("s_waitcnt vmcnt(4)" ::: "memory"); }
    else if (kt + 1 < NKT) { asm volatile("s_waitcnt vmcnt(0)" ::: "memory"); }
    __builtin_amdgcn_s_barrier();
  }

#pragma unroll
  for (int m = 0; m < 8; ++m) {
#pragma unroll
    for (int r = 0; r < 4; ++r) {
      const int row = brow + wm * 128 + m * 16 + fg * 4 + r;
#pragma unroll
      for (int n = 0; n < 4; ++n) {
        const int col = bcol + wn * 64 + n * 16 + fr;
        tmp[(size_t)row * HID + col] = f2bf(accf[m][n][r]);
      }
    }
  }
}

// ---------------- combine: out[t] = tmp[sh] + w0*tmp[s0] + w1*tmp[s1] -----------
__global__ __launch_bounds__(256) void k_combine(
    const u16* __restrict__ tmp, const int* __restrict__ slotmap,
    const float2* __restrict__ wts, float* __restrict__ out) {
  const int idx = blockIdx.x * 256 + threadIdx.x;
  const int t = idx >> 7;
  const int c = (idx & 127) << 3;
  const int s0 = slotmap[2 * t], s1 = slotmap[2 * t + 1];
  const float2 wv = wts[t];
  const short8 a = *(const short8*)(tmp + (size_t)s0 * HID + c);
  const short8 b = *(const short8*)(tmp + (size_t)s1 * HID + c);
  const short8 s = *(const short8*)(tmp + (size_t)(RBASE + t) * HID + c);
  float r[8];
#pragma unroll
  for (int j = 0; j < 8; ++j)
    r[j] = bf2f((u16)s[j]) + wv.x * bf2f((u16)a[j]) + wv.y * bf2f((u16)b[j]);
  float* po = out + (size_t)t * HID + c;
  *(float4*)po       = make_float4(r[0], r[1], r[2], r[3]);
  *(float4*)(po + 4) = make_float4(r[4], r[5], r[6], r[7]);
}

// ---------------- launch ----------------
extern "C" void kernel_launch(void* const* d_in, const int* in_sizes, int n_in,
                              void* d_out, int out_size, void* d_ws, size_t ws_size,
                              hipStream_t stream) {
  const float* x   = (const float*)d_in[0];
  const float* wg  = (const float*)d_in[1];
  const float* wgu = (const float*)d_in[2];
  const float* wdn = (const float*)d_in[3];
  const float* wsg = (const float*)d_in[4];
  const float* wsd = (const float*)d_in[5];
  float* out = (float*)d_out;

  char* ws = (char*)d_ws;
  i8*  xq    = (i8*)ws;   ws += (size_t)T_TOK * HID;
  i8*  wguq  = (i8*)ws;   ws += (size_t)NE * 1024 * HID;
  u16* wdT   = (u16*)ws;  ws += (size_t)NE * HID * ISZ * 2;
  u16* actb  = (u16*)ws;  ws += (size_t)NSLOT * ISZ * 2;
  u16* tmp   = (u16*)ws;  ws += (size_t)NSLOT * HID * 2;
  float* sxg = (float*)ws; ws += (size_t)T_TOK * 4;
  float* swc = (float*)ws; ws += (size_t)NE * 1024 * 4;
  float* pmx = (float*)ws; ws += (size_t)NE * 64 * 1024 * 4;
  int* eidx  = (int*)ws;  ws += (size_t)T_TOK * 4;
  float2* wt = (float2*)ws; ws += (size_t)T_TOK * 8;
  int* btok  = (int*)ws;  ws += (size_t)RBASE * 4;
  int* smap  = (int*)ws;  ws += (size_t)2 * T_TOK * 4;
  int* seg   = (int*)ws;  ws += 16 * 4;
  int* segc  = (int*)ws;

  k_wamax_part<<<dim3(64, NE), 256, 0, stream>>>(wgu, wsg, pmx);
  k_wamax_red<<<(NE * 1024) / 256, 256, 0, stream>>>(pmx, swc);
  k_prep<<<NB_WGUP + NB_WDN + NB_RTR, 256, 0, stream>>>(
      x, wg, wgu, wsg, wdn, wsd, swc, xq, sxg, wguq, wdT, eidx, wt);
  k_scatter<<<1, 512, 0, stream>>>(eidx, btok, smap, seg, segc);
  k_gemm_gu<<<NROWB * 4, 512, 0, stream>>>(
      xq, wguq, seg, segc, btok, sxg, swc, actb);
  k_gemm_down<<<dim3(NROWB, HID / 256), 512, 0, stream>>>(actb, wdT, seg, segc, tmp);
  k_combine<<<(T_TOK * HID / 8) / 256, 256, 0, stream>>>(tmp, smap, wt, out);
}

// Round 17
// 202.502 us; speedup vs baseline: 1.0970x; 1.0190x over previous
//
#include <hip/hip_runtime.h>
#include <hip/hip_bf16.h>
#include <cstdint>

#define T_TOK 8192
#define HID   1024
#define NE    9
#define ISZ   512
#define RBASE 18432
#define NSLOT (RBASE + T_TOK)   // 26624

#define BM 256
#define NROWB (NSLOT / BM)      // 104

typedef unsigned short u16;
typedef unsigned int   u32;
typedef signed char    i8;
typedef __attribute__((ext_vector_type(8))) short short8;
typedef __attribute__((ext_vector_type(4))) float f32x4;
typedef __attribute__((ext_vector_type(4))) int   i32x4;

__device__ __forceinline__ u16 f2bf(float f) {
  u32 u = __builtin_bit_cast(u32, f);
  return (u16)((u + 0x7fffu + ((u >> 16) & 1u)) >> 16);
}
__device__ __forceinline__ float bf2f(u16 v) {
  return __builtin_bit_cast(float, (u32)v << 16);
}
__device__ __forceinline__ int q8(float v, float inv) {
  int q = (int)__builtin_rintf(v * inv);
  return (q > 127) ? 127 : ((q < -127) ? -127 : q);
}
__device__ __forceinline__ int colp_of(int c) {
  int i = (c < 512) ? c : (c - 512);
  return (i >> 4) * 32 + ((c < 512) ? 0 : 16) + (i & 15);
}

#define STAGE(gp, lp) __builtin_amdgcn_global_load_lds( \
    (__attribute__((address_space(1))) u32*)(gp),       \
    (__attribute__((address_space(3))) u32*)(lp), 16, 0, 0)

// ---------------- per-column weight amax, stage 1: coalesced partials ----------
__global__ __launch_bounds__(256) void k_wamax_part(
    const float* __restrict__ wgu, const float* __restrict__ wsg,
    float* __restrict__ pmax) {
  const int e = blockIdx.y, hb = blockIdx.x;
  const float* src = (e < 8) ? (wgu + (size_t)e * 1048576) : wsg;
  const int wv = threadIdx.x >> 6, l = threadIdx.x & 63;
  float4 m4[4];
#pragma unroll
  for (int j = 0; j < 4; ++j) m4[j] = make_float4(0.f, 0.f, 0.f, 0.f);
  const int r0 = hb * 16 + wv * 4;
#pragma unroll
  for (int r = 0; r < 4; ++r) {
    const float* row = src + (size_t)(r0 + r) * 1024;
#pragma unroll
    for (int j = 0; j < 4; ++j) {
      const float4 v = *(const float4*)&row[j * 256 + l * 4];
      m4[j].x = fmaxf(m4[j].x, fabsf(v.x));
      m4[j].y = fmaxf(m4[j].y, fabsf(v.y));
      m4[j].z = fmaxf(m4[j].z, fabsf(v.z));
      m4[j].w = fmaxf(m4[j].w, fabsf(v.w));
    }
  }
  __shared__ float4 red[4][4][64];
#pragma unroll
  for (int j = 0; j < 4; ++j) red[wv][j][l] = m4[j];
  __syncthreads();
  const int j2 = threadIdx.x >> 6, l2 = threadIdx.x & 63;
  const float4 a = red[0][j2][l2], b = red[1][j2][l2];
  const float4 c = red[2][j2][l2], d = red[3][j2][l2];
  float4 o;
  o.x = fmaxf(fmaxf(a.x, b.x), fmaxf(c.x, d.x));
  o.y = fmaxf(fmaxf(a.y, b.y), fmaxf(c.y, d.y));
  o.z = fmaxf(fmaxf(a.z, b.z), fmaxf(c.z, d.z));
  o.w = fmaxf(fmaxf(a.w, b.w), fmaxf(c.w, d.w));
  *(float4*)&pmax[((size_t)e * 64 + hb) * 1024 + j2 * 256 + l2 * 4] = o;
}

__global__ __launch_bounds__(256) void k_wamax_red(
    const float* __restrict__ pmax, float* __restrict__ swc) {
  const int flat = blockIdx.x * 256 + threadIdx.x;   // 9216
  const int e = flat >> 10, c = flat & 1023;
  float m = 0.f;
  for (int hb = 0; hb < 64; ++hb)
    m = fmaxf(m, pmax[((size_t)e * 64 + hb) * 1024 + c]);
  swc[e * 1024 + colp_of(c)] = m * (1.f / 127.f);
}

// ---------------- k_prep (r14 fused version): transposes + router ----------------
#define NB_WGUP (32 * 8 * NE)    // 2304
#define NB_WDN  (32 * 4 * NE)    // 1152
#define NB_RTR  (T_TOK / 4)      // 2048

__global__ __launch_bounds__(256) void k_prep(
    const float* __restrict__ x, const float* __restrict__ wg,
    const float* __restrict__ wgu, const float* __restrict__ wsg,
    const float* __restrict__ wdn, const float* __restrict__ wsd,
    const float* __restrict__ swc,
    i8* __restrict__ xq, float* __restrict__ sxg,
    i8* __restrict__ wguq, u16* __restrict__ wdT,
    int* __restrict__ eidx, float2* __restrict__ wts) {
  __shared__ float tile[32][129];
  const int b = blockIdx.x;
  const int tid = threadIdx.x;

  if (b < NB_WGUP) {
    const int e = b / 256, rem = b % 256;
    const int c0 = (rem & 31) * 32, h0 = (rem >> 5) * 128;
    const float* src = (e < 8) ? (wgu + (size_t)e * HID * 1024) : wsg;
    const int hl = tid >> 1, cb = (tid & 1) * 16;
#pragma unroll
    for (int j = 0; j < 4; ++j) {
      const float4 v = *(const float4*)&src[(size_t)(h0 + hl) * 1024 + c0 + cb + j * 4];
      tile[cb + j * 4 + 0][hl] = v.x;
      tile[cb + j * 4 + 1][hl] = v.y;
      tile[cb + j * 4 + 2][hl] = v.z;
      tile[cb + j * 4 + 3][hl] = v.w;
    }
    __syncthreads();
    const int cl = tid >> 3, hb = (tid & 7) * 16;
    const int cp = colp_of(c0 + cl);
    const float inv = 1.f / swc[e * 1024 + cp];
    i8 out[16];
#pragma unroll
    for (int k = 0; k < 16; ++k) out[k] = (i8)q8(tile[cl][hb + k], inv);
    *(int4*)&wguq[((size_t)e * 1024 + cp) * 1024 + h0 + hb] = *(int4*)out;
    return;
  }
  if (b < NB_WGUP + NB_WDN) {
    const int bb = b - NB_WGUP;
    const int e = bb / 128, r2 = bb % 128;
    const int h0 = (r2 & 31) * 32, i0 = (r2 >> 5) * 128;
    const float* src = (e < 8) ? (wdn + (size_t)e * ISZ * HID) : wsd;
    const int il = tid >> 1, hb2 = (tid & 1) * 16;
#pragma unroll
    for (int j = 0; j < 4; ++j) {
      const float4 v = *(const float4*)&src[(size_t)(i0 + il) * 1024 + h0 + hb2 + j * 4];
      tile[hb2 + j * 4 + 0][il] = v.x;
      tile[hb2 + j * 4 + 1][il] = v.y;
      tile[hb2 + j * 4 + 2][il] = v.z;
      tile[hb2 + j * 4 + 3][il] = v.w;
    }
    __syncthreads();
    const int hl2 = tid >> 3, ib = (tid & 7) * 16;
    u16 ob[16];
#pragma unroll
    for (int k = 0; k < 16; ++k) ob[k] = f2bf(tile[hl2][ib + k]);
    u16* dst = &wdT[((size_t)e * HID + h0 + hl2) * ISZ + i0 + ib];
    *(int4*)dst = *(int4*)ob;
    *(int4*)(dst + 8) = *(int4*)(ob + 8);
    return;
  }
  const int t = (b - NB_WGUP - NB_WDN) * 4 + (tid >> 6);
  const int l = tid & 63;
  float a[8] = {0, 0, 0, 0, 0, 0, 0, 0};
  float vals[16];
  float am = 0.f;
  const float4* xr4 = (const float4*)(x + (size_t)t * HID);
#pragma unroll
  for (int j = 0; j < 4; ++j) {
    const float4 v = xr4[j * 64 + l];
    vals[4 * j] = v.x; vals[4 * j + 1] = v.y; vals[4 * j + 2] = v.z; vals[4 * j + 3] = v.w;
    am = fmaxf(am, fmaxf(fmaxf(fabsf(v.x), fabsf(v.y)), fmaxf(fabsf(v.z), fabsf(v.w))));
    const int h = (j * 64 + l) * 4;
#pragma unroll
    for (int i = 0; i < 4; ++i) {
      const float4 w0 = *(const float4*)&wg[(h + i) * 8];
      const float4 w1 = *(const float4*)&wg[(h + i) * 8 + 4];
      const float ev = vals[4 * j + i];
      a[0] += ev * w0.x; a[1] += ev * w0.y; a[2] += ev * w0.z; a[3] += ev * w0.w;
      a[4] += ev * w1.x; a[5] += ev * w1.y; a[6] += ev * w1.z; a[7] += ev * w1.w;
    }
  }
#pragma unroll
  for (int off = 32; off >= 1; off >>= 1) {
    am = fmaxf(am, __shfl_xor(am, off));
#pragma unroll
    for (int e2 = 0; e2 < 8; ++e2) a[e2] += __shfl_xor(a[e2], off);
  }
  const float inv = (am > 0.f) ? 127.f / am : 0.f;
  u32* xq4 = (u32*)(xq + (size_t)t * HID);
#pragma unroll
  for (int j = 0; j < 4; ++j) {
    u32 q = ((u32)(unsigned char)(i8)q8(vals[4 * j], inv)) |
            ((u32)(unsigned char)(i8)q8(vals[4 * j + 1], inv) << 8) |
            ((u32)(unsigned char)(i8)q8(vals[4 * j + 2], inv) << 16) |
            ((u32)(unsigned char)(i8)q8(vals[4 * j + 3], inv) << 24);
    xq4[j * 64 + l] = q;
  }
  if (l == 0) {
    sxg[t] = am * (1.f / 127.f);
    int ia = 0;
#pragma unroll
    for (int e2 = 1; e2 < 8; ++e2) if (a[e2] > a[ia]) ia = e2;
    int ib = (ia == 0) ? 1 : 0;
#pragma unroll
    for (int e2 = 0; e2 < 8; ++e2) if (e2 != ia && a[e2] > a[ib]) ib = e2;
    float wa = 1.f / (1.f + expf(a[ib] - a[ia]));
    eidx[t] = ia | (ib << 8);
    wts[t] = make_float2(wa, 1.f - wa);
  }
}

// ---------------- deterministic counting scatter (256-aligned segments) --------
__global__ __launch_bounds__(512) void k_scatter(
    const int* __restrict__ eidx, int* __restrict__ btok, int* __restrict__ slotmap,
    int* __restrict__ seg, int* __restrict__ segcnt) {
  __shared__ int cnt_s[8];
  __shared__ int goff_s[9];
  const int e = threadIdx.x >> 6;
  const int l = threadIdx.x & 63;

  int c1 = 0;
  for (int c = 0; c < T_TOK / 64; ++c) {
    int v = eidx[c * 64 + l];
    c1 += __popcll(__ballot((v & 255) == e)) + __popcll(__ballot(((v >> 8) & 255) == e));
  }
  if (l == 0) cnt_s[e] = c1;
  __syncthreads();
  if (threadIdx.x == 0) {
    int off = 0;
    for (int k = 0; k < 8; ++k) { goff_s[k] = off; off += (cnt_s[k] + 255) & ~255; }
    goff_s[8] = off;
  }
  __syncthreads();
  const int base0 = goff_s[e];
  const int cnt_e = cnt_s[e];
  const unsigned long long below = (l == 63) ? ~0ull >> 1 : ((1ull << l) - 1);

  int base = base0;
  for (int c = 0; c < T_TOK / 64; ++c) {
    const int t = c * 64 + l;
    const int v = eidx[t];
    const unsigned long long ma = __ballot((v & 255) == e);
    const unsigned long long mb = __ballot(((v >> 8) & 255) == e);
    if ((v & 255) == e) {
      int s = base + __popcll(ma & below);
      btok[s] = t; slotmap[2 * t] = s;
    }
    if (((v >> 8) & 255) == e) {
      int s = base + __popcll(ma) + __popcll(mb & below);
      btok[s] = t; slotmap[2 * t + 1] = s;
    }
    base += __popcll(ma) + __popcll(mb);
  }
  for (int p = cnt_e + l; p < ((cnt_e + 255) & ~255); p += 64) btok[base0 + p] = 0;
  if (threadIdx.x < 9) seg[threadIdx.x] = goff_s[threadIdx.x];
  if (threadIdx.x < 8) segcnt[threadIdx.x] = cnt_s[threadIdx.x];
}

__device__ __forceinline__ bool seg_lookup(const int* __restrict__ seg,
                                           const int* __restrict__ segcnt,
                                           int brow, int& e) {
  if (brow >= RBASE) { e = 8; return true; }
  if (brow >= seg[8]) return false;
  e = 0;
#pragma unroll
  for (int k = 1; k < 8; ++k) if (brow >= seg[k]) e = k;
  return brow < seg[e] + segcnt[e];
}

// =================================================================================
// GEMM1 (int8): 256x256 tile, K-slot=128 i8, 8 waves 4M x 2N (per-wave 64x128).
// LDS: 2-ring A + 2-ring B = 128KB. Depth-1 stage-ahead, ^(row&7) swizzle.
// =================================================================================

#define G1_STG(kt) do { const int _r = ((kt) & 1) * 32768;          \
    STAGE(sA0 + (kt) * 128, Ab + _r + 0 * 8192 + w * 1024);         \
    STAGE(sA1 + (kt) * 128, Ab + _r + 1 * 8192 + w * 1024);         \
    STAGE(sA2 + (kt) * 128, Ab + _r + 2 * 8192 + w * 1024);         \
    STAGE(sA3 + (kt) * 128, Ab + _r + 3 * 8192 + w * 1024);         \
    STAGE(sB0 + (kt) * 128, Bb + _r + 0 * 8192 + w * 1024);         \
    STAGE(sB1 + (kt) * 128, Bb + _r + 1 * 8192 + w * 1024);         \
    STAGE(sB2 + (kt) * 128, Bb + _r + 2 * 8192 + w * 1024);         \
    STAGE(sB3 + (kt) * 128, Bb + _r + 3 * 8192 + w * 1024); } while (0)

#define G1_LOADF(RG, KX) do {                                       \
    _Pragma("unroll") for (int m = 0; m < 4; ++m)                   \
      fA[m] = *(const i32x4*)&Ab[(RG) * 32768 + aBase + m * 2048 + (KX)]; \
    _Pragma("unroll") for (int n = 0; n < 8; ++n)                   \
      fB[n] = *(const i32x4*)&Bb[(RG) * 32768 + bBase + n * 2048 + (KX)]; } while (0)

#define G1_MFMA do { __builtin_amdgcn_s_setprio(1);                 \
    _Pragma("unroll") for (int m = 0; m < 4; ++m)                   \
      _Pragma("unroll") for (int n = 0; n < 8; ++n)                 \
        acc[m][n] = __builtin_amdgcn_mfma_i32_16x16x64_i8(fA[m], fB[n], acc[m][n], 0, 0, 0); \
    __builtin_amdgcn_s_setprio(0); } while (0)

__global__ __launch_bounds__(512) void k_gemm_gu(
    const i8* __restrict__ xq,      // [T][1024] i8
    const i8* __restrict__ wguq,    // [NE][1024][1024] i8 (B^T, gate/up interleaved)
    const int* __restrict__ seg, const int* __restrict__ segcnt,
    const int* __restrict__ btok, const float* __restrict__ sxg,
    const float* __restrict__ swc,  // [NE][1024] per-column scale (amax/127)
    u16* __restrict__ act)          // [NSLOT][ISZ] bf16
{
  const int bid = blockIdx.x;
  const int brow = (bid % NROWB) * BM;
  const int bcol = (bid / NROWB) * 256;
  int e;
  if (!seg_lookup(seg, segcnt, brow, e)) return;

  __shared__ __align__(16) i8 Ab[2 * 32768];   // 64 KB
  __shared__ __align__(16) i8 Bb[2 * 32768];   // 64 KB
  __shared__ float sxl[BM];
  __shared__ float swcl[256];

  const int tid = threadIdx.x;
  const int w = tid >> 6, l = tid & 63;
  const int wm = w >> 1, wn = w & 1;           // 4M x 2N -> 64x128 per wave
  const int fr = l & 15, fg = l >> 4;

  if (tid < BM) {
    const int rrow = brow + tid;
    const int tk = (e < 8) ? btok[rrow] : (rrow - RBASE);
    sxl[tid] = sxg[tk];
  } else {
    swcl[tid - 256] = swc[e * 1024 + bcol + (tid - 256)];
  }

  const int rr = w * 8 + (l >> 3);
  const int sw = ((l & 7) ^ (l >> 3)) * 16;
  int tr[4];
#pragma unroll
  for (int j = 0; j < 4; ++j) {
    const int gr = brow + j * 64 + rr;
    tr[j] = (e < 8) ? btok[gr] : (gr - RBASE);
  }
  const i8* sA0 = xq + (size_t)tr[0] * HID + sw;
  const i8* sA1 = xq + (size_t)tr[1] * HID + sw;
  const i8* sA2 = xq + (size_t)tr[2] * HID + sw;
  const i8* sA3 = xq + (size_t)tr[3] * HID + sw;
  const i8* sB0 = wguq + ((size_t)e * 1024 + bcol + 0 * 64 + rr) * HID + sw;
  const i8* sB1 = wguq + ((size_t)e * 1024 + bcol + 1 * 64 + rr) * HID + sw;
  const i8* sB2 = wguq + ((size_t)e * 1024 + bcol + 2 * 64 + rr) * HID + sw;
  const i8* sB3 = wguq + ((size_t)e * 1024 + bcol + 3 * 64 + rr) * HID + sw;

  const int aBase = (wm * 64 + fr) * 128;
  const int bBase = (wn * 128 + fr) * 128;
  const int kx0 = (fg ^ (fr & 7)) * 16;
  const int kx1 = kx0 ^ 64;

  i32x4 acc[4][8];
#pragma unroll
  for (int m = 0; m < 4; ++m)
#pragma unroll
    for (int n = 0; n < 8; ++n) acc[m][n] = (i32x4){0, 0, 0, 0};
  i32x4 fA[4], fB[8];

  const int NKT = HID / 128;   // 8 slots
  G1_STG(0);
  asm volatile("s_waitcnt vmcnt(0)" ::: "memory");
  __builtin_amdgcn_s_barrier();
  for (int s = 0; s < NKT; ++s) {
    const int rg = s & 1;
    if (s + 1 < NKT) G1_STG(s + 1);
    G1_LOADF(rg, kx0);
    asm volatile("s_waitcnt lgkmcnt(0)" ::: "memory");
    __builtin_amdgcn_sched_barrier(0);
    G1_MFMA;
    G1_LOADF(rg, kx1);
    asm volatile("s_waitcnt lgkmcnt(0)" ::: "memory");
    __builtin_amdgcn_sched_barrier(0);
    G1_MFMA;
    asm volatile("s_waitcnt vmcnt(0)" ::: "memory");
    __builtin_amdgcn_s_barrier();
  }

#pragma unroll
  for (int m = 0; m < 4; ++m) {
#pragma unroll
    for (int p = 0; p < 4; ++p) {
      const i32x4 gI = acc[m][2 * p], uI = acc[m][2 * p + 1];
      const int col = ((bcol + wn * 128) >> 1) + p * 16 + fr;
      const float swg = swcl[wn * 128 + p * 32 + fr];
      const float swu = swcl[wn * 128 + p * 32 + 16 + fr];
#pragma unroll
      for (int r = 0; r < 4; ++r) {
        const int row_l = wm * 64 + m * 16 + fg * 4 + r;
        const float sx = sxl[row_l];
        const float gate = (float)gI[r] * (sx * swg);
        const float up   = (float)uI[r] * (sx * swu);
        const float sv = gate / (1.f + __expf(-gate));
        act[(size_t)(brow + row_l) * ISZ + col] = f2bf(sv * up);
      }
    }
  }
}

// =================================================================================
// GEMM2 (bf16): mirror of GEMM1 structure. 256x256 tile, K-slot=64 bf16 (128-B
// rows, 8x16B chunks), 8 waves 4M x 2N (per-wave 64x128), 2-ring LDS (128 KB),
// depth-1 stage-ahead, ^(row&7) swizzle. Per slot: 2 halves (K32 each), each
// {12 ds_read_b128 -> lgkm(0) -> 32 bf16 MFMA}.
// =================================================================================

#define G2_STG(kt) do { const int _r = ((kt) & 1) * 16384;          \
    STAGE(dA0 + (kt) * 64, As2 + _r + 0 * 4096 + w * 512);          \
    STAGE(dA1 + (kt) * 64, As2 + _r + 1 * 4096 + w * 512);          \
    STAGE(dA2 + (kt) * 64, As2 + _r + 2 * 4096 + w * 512);          \
    STAGE(dA3 + (kt) * 64, As2 + _r + 3 * 4096 + w * 512);          \
    STAGE(dB0 + (kt) * 64, Bs2 + _r + 0 * 4096 + w * 512);          \
    STAGE(dB1 + (kt) * 64, Bs2 + _r + 1 * 4096 + w * 512);          \
    STAGE(dB2 + (kt) * 64, Bs2 + _r + 2 * 4096 + w * 512);          \
    STAGE(dB3 + (kt) * 64, Bs2 + _r + 3 * 4096 + w * 512); } while (0)

#define G2_LOADF(RG, KX) do {                                       \
    _Pragma("unroll") for (int m = 0; m < 4; ++m)                   \
      gA[m] = *(const short8*)&As2[(RG) * 16384 + aBase + m * 1024 + (KX)]; \
    _Pragma("unroll") for (int n = 0; n < 8; ++n)                   \
      gB[n] = *(const short8*)&Bs2[(RG) * 16384 + bBase + n * 1024 + (KX)]; } while (0)

#define G2_MFMA do { __builtin_amdgcn_s_setprio(1);                 \
    _Pragma("unroll") for (int m = 0; m < 4; ++m)                   \
      _Pragma("unroll") for (int n = 0; n < 8; ++n)                 \
        accf[m][n] = __builtin_amdgcn_mfma_f32_16x16x32_bf16(gA[m], gB[n], accf[m][n], 0, 0, 0); \
    __builtin_amdgcn_s_setprio(0); } while (0)

__global__ __launch_bounds__(512) void k_gemm_down(
    const u16* __restrict__ act,   // [NSLOT][512] bf16
    const u16* __restrict__ wdT,   // [NE][1024][512] bf16
    const int* __restrict__ seg, const int* __restrict__ segcnt,
    u16* __restrict__ tmp) {
  const int bid = blockIdx.x;
  const int brow = (bid % NROWB) * BM;
  const int bcol = (bid / NROWB) * 256;
  int e;
  if (!seg_lookup(seg, segcnt, brow, e)) return;

  __shared__ __align__(16) u16 As2[2 * 16384];  // 64 KB
  __shared__ __align__(16) u16 Bs2[2 * 16384];  // 64 KB

  const int tid = threadIdx.x;
  const int w = tid >> 6, l = tid & 63;
  const int wm = w >> 1, wn = w & 1;            // 4M x 2N -> 64x128 per wave
  const int fr = l & 15, fg = l >> 4;

  const int rr = w * 8 + (l >> 3);
  const int sw = ((l & 7) ^ (l >> 3)) * 8;      // 16B chunk in elems
  const u16* dA0 = act + (size_t)(brow + 0 * 64 + rr) * ISZ + sw;
  const u16* dA1 = act + (size_t)(brow + 1 * 64 + rr) * ISZ + sw;
  const u16* dA2 = act + (size_t)(brow + 2 * 64 + rr) * ISZ + sw;
  const u16* dA3 = act + (size_t)(brow + 3 * 64 + rr) * ISZ + sw;
  const u16* dB0 = wdT + ((size_t)e * 1024 + bcol + 0 * 64 + rr) * ISZ + sw;
  const u16* dB1 = wdT + ((size_t)e * 1024 + bcol + 1 * 64 + rr) * ISZ + sw;
  const u16* dB2 = wdT + ((size_t)e * 1024 + bcol + 2 * 64 + rr) * ISZ + sw;
  const u16* dB3 = wdT + ((size_t)e * 1024 + bcol + 3 * 64 + rr) * ISZ + sw;

  const int aBase = (wm * 64 + fr) * 64;
  const int bBase = (wn * 128 + fr) * 64;
  const int kx0 = (fg ^ (fr & 7)) * 8;
  const int kx1 = kx0 ^ 32;

  f32x4 accf[4][8];
#pragma unroll
  for (int m = 0; m < 4; ++m)
#pragma unroll
    for (int n = 0; n < 8; ++n) accf[m][n] = (f32x4){0.f, 0.f, 0.f, 0.f};
  short8 gA[4], gB[8];

  const int NKT = ISZ / 64;   // 8 slots
  G2_STG(0);
  asm volatile("s_waitcnt vmcnt(0)" ::: "memory");
  __builtin_amdgcn_s_barrier();
  for (int s = 0; s < NKT; ++s) {
    const int rg = s & 1;
    if (s + 1 < NKT) G2_STG(s + 1);
    G2_LOADF(rg, kx0);
    asm volatile("s_waitcnt lgkmcnt(0)" ::: "memory");
    __builtin_amdgcn_sched_barrier(0);
    G2_MFMA;
    G2_LOADF(rg, kx1);
    asm volatile("s_waitcnt lgkmcnt(0)" ::: "memory");
    __builtin_amdgcn_sched_barrier(0);
    G2_MFMA;
    asm volatile("s_waitcnt vmcnt(0)" ::: "memory");
    __builtin_amdgcn_s_barrier();
  }

#pragma unroll
  for (int m = 0; m < 4; ++m) {
#pragma unroll
    for (int r = 0; r < 4; ++r) {
      const int row = brow + wm * 64 + m * 16 + fg * 4 + r;
#pragma unroll
      for (int n = 0; n < 8; ++n) {
        const int col = bcol + wn * 128 + n * 16 + fr;
        tmp[(size_t)row * HID + col] = f2bf(accf[m][n][r]);
      }
    }
  }
}

// ---------------- combine: out[t] = tmp[sh] + w0*tmp[s0] + w1*tmp[s1] -----------
__global__ __launch_bounds__(256) void k_combine(
    const u16* __restrict__ tmp, const int* __restrict__ slotmap,
    const float2* __restrict__ wts, float* __restrict__ out) {
  const int idx = blockIdx.x * 256 + threadIdx.x;
  const int t = idx >> 7;
  const int c = (idx & 127) << 3;
  const int s0 = slotmap[2 * t], s1 = slotmap[2 * t + 1];
  const float2 wv = wts[t];
  const short8 a = *(const short8*)(tmp + (size_t)s0 * HID + c);
  const short8 b = *(const short8*)(tmp + (size_t)s1 * HID + c);
  const short8 s = *(const short8*)(tmp + (size_t)(RBASE + t) * HID + c);
  float r[8];
#pragma unroll
  for (int j = 0; j < 8; ++j)
    r[j] = bf2f((u16)s[j]) + wv.x * bf2f((u16)a[j]) + wv.y * bf2f((u16)b[j]);
  float* po = out + (size_t)t * HID + c;
  *(float4*)po       = make_float4(r[0], r[1], r[2], r[3]);
  *(float4*)(po + 4) = make_float4(r[4], r[5], r[6], r[7]);
}

// ---------------- launch ----------------
extern "C" void kernel_launch(void* const* d_in, const int* in_sizes, int n_in,
                              void* d_out, int out_size, void* d_ws, size_t ws_size,
                              hipStream_t stream) {
  const float* x   = (const float*)d_in[0];
  const float* wg  = (const float*)d_in[1];
  const float* wgu = (const float*)d_in[2];
  const float* wdn = (const float*)d_in[3];
  const float* wsg = (const float*)d_in[4];
  const float* wsd = (const float*)d_in[5];
  float* out = (float*)d_out;

  char* ws = (char*)d_ws;
  i8*  xq    = (i8*)ws;   ws += (size_t)T_TOK * HID;
  i8*  wguq  = (i8*)ws;   ws += (size_t)NE * 1024 * HID;
  u16* wdT   = (u16*)ws;  ws += (size_t)NE * HID * ISZ * 2;
  u16* actb  = (u16*)ws;  ws += (size_t)NSLOT * ISZ * 2;
  u16* tmp   = (u16*)ws;  ws += (size_t)NSLOT * HID * 2;
  float* sxg = (float*)ws; ws += (size_t)T_TOK * 4;
  float* swc = (float*)ws; ws += (size_t)NE * 1024 * 4;
  float* pmx = (float*)ws; ws += (size_t)NE * 64 * 1024 * 4;
  int* eidx  = (int*)ws;  ws += (size_t)T_TOK * 4;
  float2* wt = (float2*)ws; ws += (size_t)T_TOK * 8;
  int* btok  = (int*)ws;  ws += (size_t)RBASE * 4;
  int* smap  = (int*)ws;  ws += (size_t)2 * T_TOK * 4;
  int* seg   = (int*)ws;  ws += 16 * 4;
  int* segc  = (int*)ws;

  k_wamax_part<<<dim3(64, NE), 256, 0, stream>>>(wgu, wsg, pmx);
  k_wamax_red<<<(NE * 1024) / 256, 256, 0, stream>>>(pmx, swc);
  k_prep<<<NB_WGUP + NB_WDN + NB_RTR, 256, 0, stream>>>(
      x, wg, wgu, wsg, wdn, wsd, swc, xq, sxg, wguq, wdT, eidx, wt);
  k_scatter<<<1, 512, 0, stream>>>(eidx, btok, smap, seg, segc);
  k_gemm_gu<<<NROWB * 4, 512, 0, stream>>>(
      xq, wguq, seg, segc, btok, sxg, swc, actb);
  k_gemm_down<<<NROWB * 4, 512, 0, stream>>>(actb, wdT, seg, segc, tmp);
  k_combine<<<(T_TOK * HID / 8) / 256, 256, 0, stream>>>(tmp, smap, wt, out);
}

// Round 18
// 201.178 us; speedup vs baseline: 1.1043x; 1.0066x over previous
//
#include <hip/hip_runtime.h>
#include <hip/hip_bf16.h>
#include <cstdint>

#define T_TOK 8192
#define HID   1024
#define NE    9
#define ISZ   512
#define RBASE 18432
#define NSLOT (RBASE + T_TOK)   // 26624

#define BM 256
#define NROWB (NSLOT / BM)      // 104

typedef unsigned short u16;
typedef unsigned int   u32;
typedef signed char    i8;
typedef __attribute__((ext_vector_type(8))) short short8;
typedef __attribute__((ext_vector_type(4))) float f32x4;
typedef __attribute__((ext_vector_type(4))) int   i32x4;

__device__ __forceinline__ u16 f2bf(float f) {
  u32 u = __builtin_bit_cast(u32, f);
  return (u16)((u + 0x7fffu + ((u >> 16) & 1u)) >> 16);
}
__device__ __forceinline__ float bf2f(u16 v) {
  return __builtin_bit_cast(float, (u32)v << 16);
}
__device__ __forceinline__ int q8(float v, float inv) {
  int q = (int)__builtin_rintf(v * inv);
  return (q > 127) ? 127 : ((q < -127) ? -127 : q);
}
__device__ __forceinline__ int colp_of(int c) {
  int i = (c < 512) ? c : (c - 512);
  return (i >> 4) * 32 + ((c < 512) ? 0 : 16) + (i & 15);
}

#define STAGE(gp, lp) __builtin_amdgcn_global_load_lds( \
    (__attribute__((address_space(1))) u32*)(gp),       \
    (__attribute__((address_space(3))) u32*)(lp), 16, 0, 0)

// ---------------- single-kernel per-column weight amax (spread atomicMax) -------
// grid (64, NE): block = 16 rows x 1024 cols; block-reduce then atomicMax into
// swc_i[e*1024 + colp] (raw amax bits; max is order-independent -> deterministic).
__global__ __launch_bounds__(256) void k_wamax(
    const float* __restrict__ wgu, const float* __restrict__ wsg,
    int* __restrict__ swc_i) {
  const int e = blockIdx.y, hb = blockIdx.x;
  const float* src = (e < 8) ? (wgu + (size_t)e * 1048576) : wsg;
  const int wv = threadIdx.x >> 6, l = threadIdx.x & 63;
  float4 m4[4];
#pragma unroll
  for (int j = 0; j < 4; ++j) m4[j] = make_float4(0.f, 0.f, 0.f, 0.f);
  const int r0 = hb * 16 + wv * 4;
#pragma unroll
  for (int r = 0; r < 4; ++r) {
    const float* row = src + (size_t)(r0 + r) * 1024;
#pragma unroll
    for (int j = 0; j < 4; ++j) {
      const float4 v = *(const float4*)&row[j * 256 + l * 4];
      m4[j].x = fmaxf(m4[j].x, fabsf(v.x));
      m4[j].y = fmaxf(m4[j].y, fabsf(v.y));
      m4[j].z = fmaxf(m4[j].z, fabsf(v.z));
      m4[j].w = fmaxf(m4[j].w, fabsf(v.w));
    }
  }
  __shared__ float4 red[4][4][64];
#pragma unroll
  for (int j = 0; j < 4; ++j) red[wv][j][l] = m4[j];
  __syncthreads();
  const int j2 = threadIdx.x >> 6, l2 = threadIdx.x & 63;
  const float4 a = red[0][j2][l2], b = red[1][j2][l2];
  const float4 c = red[2][j2][l2], d = red[3][j2][l2];
  float o[4];
  o[0] = fmaxf(fmaxf(a.x, b.x), fmaxf(c.x, d.x));
  o[1] = fmaxf(fmaxf(a.y, b.y), fmaxf(c.y, d.y));
  o[2] = fmaxf(fmaxf(a.z, b.z), fmaxf(c.z, d.z));
  o[3] = fmaxf(fmaxf(a.w, b.w), fmaxf(c.w, d.w));
  const int cbase = j2 * 256 + l2 * 4;
#pragma unroll
  for (int k = 0; k < 4; ++k)
    atomicMax(&swc_i[e * 1024 + colp_of(cbase + k)], __float_as_int(o[k]));
}

// ---------------- k_prep: fused wide-tile transposes + router ----------------
#define NB_WGUP (128 * NE)   // 1152 (16 c-blocks x 8 h-blocks per expert)
#define NB_WDN  (64 * NE)    // 576  (16 h-blocks x 4 i-blocks per expert)
#define NB_RTR  (T_TOK / 4)  // 2048

__global__ __launch_bounds__(256) void k_prep(
    const float* __restrict__ x, const float* __restrict__ wg,
    const float* __restrict__ wgu, const float* __restrict__ wsg,
    const float* __restrict__ wdn, const float* __restrict__ wsd,
    const int* __restrict__ swc_i,
    i8* __restrict__ xq, float* __restrict__ sxg,
    i8* __restrict__ wguq, u16* __restrict__ wdT,
    int* __restrict__ eidx, float2* __restrict__ wts) {
  __shared__ float tile[64][130];
  const int b = blockIdx.x;
  const int tid = threadIdx.x;

  if (b < NB_WGUP) {
    // 128h x 64c tile -> i8 [e][colp][h]; 8 float4 loads in flight per thread
    const int e = b / 128, rem = b % 128;
    const int c0 = (rem & 15) * 64, h0 = (rem >> 4) * 128;
    const float* src = (e < 8) ? (wgu + (size_t)e * HID * 1024) : wsg;
    const int hl = tid >> 1, cb = (tid & 1) * 32;
    float4 v[8];
#pragma unroll
    for (int j = 0; j < 8; ++j)
      v[j] = *(const float4*)&src[(size_t)(h0 + hl) * 1024 + c0 + cb + j * 4];
#pragma unroll
    for (int j = 0; j < 8; ++j) {
      tile[cb + j * 4 + 0][hl] = v[j].x;
      tile[cb + j * 4 + 1][hl] = v[j].y;
      tile[cb + j * 4 + 2][hl] = v[j].z;
      tile[cb + j * 4 + 3][hl] = v[j].w;
    }
    __syncthreads();
    const int cl = tid >> 2, hb = (tid & 3) * 32;
    const int cp = colp_of(c0 + cl);
    const float inv = 127.f / __int_as_float(swc_i[e * 1024 + cp]);
    i8 out[32];
#pragma unroll
    for (int k = 0; k < 32; ++k) out[k] = (i8)q8(tile[cl][hb + k], inv);
    i8* dst = &wguq[((size_t)e * 1024 + cp) * 1024 + h0 + hb];
    *(int4*)dst = *(int4*)out;
    *(int4*)(dst + 16) = *(int4*)(out + 16);
    return;
  }
  if (b < NB_WGUP + NB_WDN) {
    // 128i x 64h tile -> bf16 [e][h][i]
    const int bb = b - NB_WGUP;
    const int e = bb / 64, rem = bb % 64;
    const int h0 = (rem & 15) * 64, i0 = (rem >> 4) * 128;
    const float* src = (e < 8) ? (wdn + (size_t)e * ISZ * HID) : wsd;
    const int il = tid >> 1, hb = (tid & 1) * 32;
    float4 v[8];
#pragma unroll
    for (int j = 0; j < 8; ++j)
      v[j] = *(const float4*)&src[(size_t)(i0 + il) * 1024 + h0 + hb + j * 4];
#pragma unroll
    for (int j = 0; j < 8; ++j) {
      tile[hb + j * 4 + 0][il] = v[j].x;
      tile[hb + j * 4 + 1][il] = v[j].y;
      tile[hb + j * 4 + 2][il] = v[j].z;
      tile[hb + j * 4 + 3][il] = v[j].w;
    }
    __syncthreads();
    const int hl = tid >> 2, ib = (tid & 3) * 32;
    u16 ob[32];
#pragma unroll
    for (int k = 0; k < 32; ++k) ob[k] = f2bf(tile[hl][ib + k]);
    u16* dst = &wdT[((size_t)e * HID + h0 + hl) * ISZ + i0 + ib];
    *(int4*)dst        = *(int4*)ob;
    *(int4*)(dst + 8)  = *(int4*)(ob + 8);
    *(int4*)(dst + 16) = *(int4*)(ob + 16);
    *(int4*)(dst + 24) = *(int4*)(ob + 24);
    return;
  }
  // router: 4 tokens/block; fused per-row amax quant of x
  const int t = (b - NB_WGUP - NB_WDN) * 4 + (tid >> 6);
  const int l = tid & 63;
  float a[8] = {0, 0, 0, 0, 0, 0, 0, 0};
  float vals[16];
  float am = 0.f;
  const float4* xr4 = (const float4*)(x + (size_t)t * HID);
#pragma unroll
  for (int j = 0; j < 4; ++j) {
    const float4 v = xr4[j * 64 + l];
    vals[4 * j] = v.x; vals[4 * j + 1] = v.y; vals[4 * j + 2] = v.z; vals[4 * j + 3] = v.w;
    am = fmaxf(am, fmaxf(fmaxf(fabsf(v.x), fabsf(v.y)), fmaxf(fabsf(v.z), fabsf(v.w))));
    const int h = (j * 64 + l) * 4;
#pragma unroll
    for (int i = 0; i < 4; ++i) {
      const float4 w0 = *(const float4*)&wg[(h + i) * 8];
      const float4 w1 = *(const float4*)&wg[(h + i) * 8 + 4];
      const float ev = vals[4 * j + i];
      a[0] += ev * w0.x; a[1] += ev * w0.y; a[2] += ev * w0.z; a[3] += ev * w0.w;
      a[4] += ev * w1.x; a[5] += ev * w1.y; a[6] += ev * w1.z; a[7] += ev * w1.w;
    }
  }
#pragma unroll
  for (int off = 32; off >= 1; off >>= 1) {
    am = fmaxf(am, __shfl_xor(am, off));
#pragma unroll
    for (int e2 = 0; e2 < 8; ++e2) a[e2] += __shfl_xor(a[e2], off);
  }
  const float inv = (am > 0.f) ? 127.f / am : 0.f;
  u32* xq4 = (u32*)(xq + (size_t)t * HID);
#pragma unroll
  for (int j = 0; j < 4; ++j) {
    u32 q = ((u32)(unsigned char)(i8)q8(vals[4 * j], inv)) |
            ((u32)(unsigned char)(i8)q8(vals[4 * j + 1], inv) << 8) |
            ((u32)(unsigned char)(i8)q8(vals[4 * j + 2], inv) << 16) |
            ((u32)(unsigned char)(i8)q8(vals[4 * j + 3], inv) << 24);
    xq4[j * 64 + l] = q;
  }
  if (l == 0) {
    sxg[t] = am * (1.f / 127.f);
    int ia = 0;
#pragma unroll
    for (int e2 = 1; e2 < 8; ++e2) if (a[e2] > a[ia]) ia = e2;
    int ib = (ia == 0) ? 1 : 0;
#pragma unroll
    for (int e2 = 0; e2 < 8; ++e2) if (e2 != ia && a[e2] > a[ib]) ib = e2;
    float wa = 1.f / (1.f + expf(a[ib] - a[ia]));
    eidx[t] = ia | (ib << 8);
    wts[t] = make_float2(wa, 1.f - wa);
  }
}

// ---------------- deterministic counting scatter (256-aligned segments) --------
__global__ __launch_bounds__(512) void k_scatter(
    const int* __restrict__ eidx, int* __restrict__ btok, int* __restrict__ slotmap,
    int* __restrict__ seg, int* __restrict__ segcnt) {
  __shared__ int cnt_s[8];
  __shared__ int goff_s[9];
  const int e = threadIdx.x >> 6;
  const int l = threadIdx.x & 63;

  int c1 = 0;
  for (int c = 0; c < T_TOK / 64; ++c) {
    int v = eidx[c * 64 + l];
    c1 += __popcll(__ballot((v & 255) == e)) + __popcll(__ballot(((v >> 8) & 255) == e));
  }
  if (l == 0) cnt_s[e] = c1;
  __syncthreads();
  if (threadIdx.x == 0) {
    int off = 0;
    for (int k = 0; k < 8; ++k) { goff_s[k] = off; off += (cnt_s[k] + 255) & ~255; }
    goff_s[8] = off;
  }
  __syncthreads();
  const int base0 = goff_s[e];
  const int cnt_e = cnt_s[e];
  const unsigned long long below = (l == 63) ? ~0ull >> 1 : ((1ull << l) - 1);

  int base = base0;
  for (int c = 0; c < T_TOK / 64; ++c) {
    const int t = c * 64 + l;
    const int v = eidx[t];
    const unsigned long long ma = __ballot((v & 255) == e);
    const unsigned long long mb = __ballot(((v >> 8) & 255) == e);
    if ((v & 255) == e) {
      int s = base + __popcll(ma & below);
      btok[s] = t; slotmap[2 * t] = s;
    }
    if (((v >> 8) & 255) == e) {
      int s = base + __popcll(ma) + __popcll(mb & below);
      btok[s] = t; slotmap[2 * t + 1] = s;
    }
    base += __popcll(ma) + __popcll(mb);
  }
  for (int p = cnt_e + l; p < ((cnt_e + 255) & ~255); p += 64) btok[base0 + p] = 0;
  if (threadIdx.x < 9) seg[threadIdx.x] = goff_s[threadIdx.x];
  if (threadIdx.x < 8) segcnt[threadIdx.x] = cnt_s[threadIdx.x];
}

__device__ __forceinline__ bool seg_lookup(const int* __restrict__ seg,
                                           const int* __restrict__ segcnt,
                                           int brow, int& e) {
  if (brow >= RBASE) { e = 8; return true; }
  if (brow >= seg[8]) return false;
  e = 0;
#pragma unroll
  for (int k = 1; k < 8; ++k) if (brow >= seg[k]) e = k;
  return brow < seg[e] + segcnt[e];
}

// =================================================================================
// GEMM1 (int8): 256x256 tile, K-slot=128 i8, 8 waves 4M x 2N (per-wave 64x128).
// LDS: 2-ring A + 2-ring B = 128KB. Depth-1 stage-ahead, ^(row&7) swizzle.
// =================================================================================

#define G1_STG(kt) do { const int _r = ((kt) & 1) * 32768;          \
    STAGE(sA0 + (kt) * 128, Ab + _r + 0 * 8192 + w * 1024);         \
    STAGE(sA1 + (kt) * 128, Ab + _r + 1 * 8192 + w * 1024);         \
    STAGE(sA2 + (kt) * 128, Ab + _r + 2 * 8192 + w * 1024);         \
    STAGE(sA3 + (kt) * 128, Ab + _r + 3 * 8192 + w * 1024);         \
    STAGE(sB0 + (kt) * 128, Bb + _r + 0 * 8192 + w * 1024);         \
    STAGE(sB1 + (kt) * 128, Bb + _r + 1 * 8192 + w * 1024);         \
    STAGE(sB2 + (kt) * 128, Bb + _r + 2 * 8192 + w * 1024);         \
    STAGE(sB3 + (kt) * 128, Bb + _r + 3 * 8192 + w * 1024); } while (0)

#define G1_LOADF(RG, KX) do {                                       \
    _Pragma("unroll") for (int m = 0; m < 4; ++m)                   \
      fA[m] = *(const i32x4*)&Ab[(RG) * 32768 + aBase + m * 2048 + (KX)]; \
    _Pragma("unroll") for (int n = 0; n < 8; ++n)                   \
      fB[n] = *(const i32x4*)&Bb[(RG) * 32768 + bBase + n * 2048 + (KX)]; } while (0)

#define G1_MFMA do { __builtin_amdgcn_s_setprio(1);                 \
    _Pragma("unroll") for (int m = 0; m < 4; ++m)                   \
      _Pragma("unroll") for (int n = 0; n < 8; ++n)                 \
        acc[m][n] = __builtin_amdgcn_mfma_i32_16x16x64_i8(fA[m], fB[n], acc[m][n], 0, 0, 0); \
    __builtin_amdgcn_s_setprio(0); } while (0)

__global__ __launch_bounds__(512) void k_gemm_gu(
    const i8* __restrict__ xq,      // [T][1024] i8
    const i8* __restrict__ wguq,    // [NE][1024][1024] i8 (B^T, gate/up interleaved)
    const int* __restrict__ seg, const int* __restrict__ segcnt,
    const int* __restrict__ btok, const float* __restrict__ sxg,
    const int* __restrict__ swc_i,  // [NE][1024] raw col amax bits
    u16* __restrict__ act)          // [NSLOT][ISZ] bf16
{
  const int bid = blockIdx.x;
  const int brow = (bid % NROWB) * BM;
  const int bcol = (bid / NROWB) * 256;
  int e;
  if (!seg_lookup(seg, segcnt, brow, e)) return;

  __shared__ __align__(16) i8 Ab[2 * 32768];   // 64 KB
  __shared__ __align__(16) i8 Bb[2 * 32768];   // 64 KB
  __shared__ float sxl[BM];
  __shared__ float swcl[256];

  const int tid = threadIdx.x;
  const int w = tid >> 6, l = tid & 63;
  const int wm = w >> 1, wn = w & 1;           // 4M x 2N -> 64x128 per wave
  const int fr = l & 15, fg = l >> 4;

  if (tid < BM) {
    const int rrow = brow + tid;
    const int tk = (e < 8) ? btok[rrow] : (rrow - RBASE);
    sxl[tid] = sxg[tk];
  } else {
    swcl[tid - 256] = __int_as_float(swc_i[e * 1024 + bcol + (tid - 256)]) * (1.f / 127.f);
  }

  const int rr = w * 8 + (l >> 3);
  const int sw = ((l & 7) ^ (l >> 3)) * 16;
  int tr[4];
#pragma unroll
  for (int j = 0; j < 4; ++j) {
    const int gr = brow + j * 64 + rr;
    tr[j] = (e < 8) ? btok[gr] : (gr - RBASE);
  }
  const i8* sA0 = xq + (size_t)tr[0] * HID + sw;
  const i8* sA1 = xq + (size_t)tr[1] * HID + sw;
  const i8* sA2 = xq + (size_t)tr[2] * HID + sw;
  const i8* sA3 = xq + (size_t)tr[3] * HID + sw;
  const i8* sB0 = wguq + ((size_t)e * 1024 + bcol + 0 * 64 + rr) * HID + sw;
  const i8* sB1 = wguq + ((size_t)e * 1024 + bcol + 1 * 64 + rr) * HID + sw;
  const i8* sB2 = wguq + ((size_t)e * 1024 + bcol + 2 * 64 + rr) * HID + sw;
  const i8* sB3 = wguq + ((size_t)e * 1024 + bcol + 3 * 64 + rr) * HID + sw;

  const int aBase = (wm * 64 + fr) * 128;
  const int bBase = (wn * 128 + fr) * 128;
  const int kx0 = (fg ^ (fr & 7)) * 16;
  const int kx1 = kx0 ^ 64;

  i32x4 acc[4][8];
#pragma unroll
  for (int m = 0; m < 4; ++m)
#pragma unroll
    for (int n = 0; n < 8; ++n) acc[m][n] = (i32x4){0, 0, 0, 0};
  i32x4 fA[4], fB[8];

  const int NKT = HID / 128;   // 8 slots
  G1_STG(0);
  asm volatile("s_waitcnt vmcnt(0)" ::: "memory");
  __builtin_amdgcn_s_barrier();
  for (int s = 0; s < NKT; ++s) {
    const int rg = s & 1;
    if (s + 1 < NKT) G1_STG(s + 1);
    G1_LOADF(rg, kx0);
    asm volatile("s_waitcnt lgkmcnt(0)" ::: "memory");
    __builtin_amdgcn_sched_barrier(0);
    G1_MFMA;
    G1_LOADF(rg, kx1);
    asm volatile("s_waitcnt lgkmcnt(0)" ::: "memory");
    __builtin_amdgcn_sched_barrier(0);
    G1_MFMA;
    asm volatile("s_waitcnt vmcnt(0)" ::: "memory");
    __builtin_amdgcn_s_barrier();
  }

#pragma unroll
  for (int m = 0; m < 4; ++m) {
#pragma unroll
    for (int p = 0; p < 4; ++p) {
      const i32x4 gI = acc[m][2 * p], uI = acc[m][2 * p + 1];
      const int col = ((bcol + wn * 128) >> 1) + p * 16 + fr;
      const float swg = swcl[wn * 128 + p * 32 + fr];
      const float swu = swcl[wn * 128 + p * 32 + 16 + fr];
#pragma unroll
      for (int r = 0; r < 4; ++r) {
        const int row_l = wm * 64 + m * 16 + fg * 4 + r;
        const float sx = sxl[row_l];
        const float gate = (float)gI[r] * (sx * swg);
        const float up   = (float)uI[r] * (sx * swu);
        const float sv = gate / (1.f + __expf(-gate));
        act[(size_t)(brow + row_l) * ISZ + col] = f2bf(sv * up);
      }
    }
  }
}

// =================================================================================
// GEMM2 (bf16): mirror of GEMM1. 256x256 tile, K-slot=64 bf16 (128-B rows),
// 8 waves 4M x 2N (64x128/wave), 2-ring LDS, depth-1 stage-ahead, ^(row&7) swizzle.
// =================================================================================

#define G2_STG(kt) do { const int _r = ((kt) & 1) * 16384;          \
    STAGE(dA0 + (kt) * 64, As2 + _r + 0 * 4096 + w * 512);          \
    STAGE(dA1 + (kt) * 64, As2 + _r + 1 * 4096 + w * 512);          \
    STAGE(dA2 + (kt) * 64, As2 + _r + 2 * 4096 + w * 512);          \
    STAGE(dA3 + (kt) * 64, As2 + _r + 3 * 4096 + w * 512);          \
    STAGE(dB0 + (kt) * 64, Bs2 + _r + 0 * 4096 + w * 512);          \
    STAGE(dB1 + (kt) * 64, Bs2 + _r + 1 * 4096 + w * 512);          \
    STAGE(dB2 + (kt) * 64, Bs2 + _r + 2 * 4096 + w * 512);          \
    STAGE(dB3 + (kt) * 64, Bs2 + _r + 3 * 4096 + w * 512); } while (0)

#define G2_LOADF(RG, KX) do {                                       \
    _Pragma("unroll") for (int m = 0; m < 4; ++m)                   \
      gA[m] = *(const short8*)&As2[(RG) * 16384 + aBase + m * 1024 + (KX)]; \
    _Pragma("unroll") for (int n = 0; n < 8; ++n)                   \
      gB[n] = *(const short8*)&Bs2[(RG) * 16384 + bBase + n * 1024 + (KX)]; } while (0)

#define G2_MFMA do { __builtin_amdgcn_s_setprio(1);                 \
    _Pragma("unroll") for (int m = 0; m < 4; ++m)                   \
      _Pragma("unroll") for (int n = 0; n < 8; ++n)                 \
        accf[m][n] = __builtin_amdgcn_mfma_f32_16x16x32_bf16(gA[m], gB[n], accf[m][n], 0, 0, 0); \
    __builtin_amdgcn_s_setprio(0); } while (0)

__global__ __launch_bounds__(512) void k_gemm_down(
    const u16* __restrict__ act,   // [NSLOT][512] bf16
    const u16* __restrict__ wdT,   // [NE][1024][512] bf16
    const int* __restrict__ seg, const int* __restrict__ segcnt,
    u16* __restrict__ tmp) {
  const int bid = blockIdx.x;
  const int brow = (bid % NROWB) * BM;
  const int bcol = (bid / NROWB) * 256;
  int e;
  if (!seg_lookup(seg, segcnt, brow, e)) return;

  __shared__ __align__(16) u16 As2[2 * 16384];  // 64 KB
  __shared__ __align__(16) u16 Bs2[2 * 16384];  // 64 KB

  const int tid = threadIdx.x;
  const int w = tid >> 6, l = tid & 63;
  const int wm = w >> 1, wn = w & 1;            // 4M x 2N -> 64x128 per wave
  const int fr = l & 15, fg = l >> 4;

  const int rr = w * 8 + (l >> 3);
  const int sw = ((l & 7) ^ (l >> 3)) * 8;      // 16B chunk in elems
  const u16* dA0 = act + (size_t)(brow + 0 * 64 + rr) * ISZ + sw;
  const u16* dA1 = act + (size_t)(brow + 1 * 64 + rr) * ISZ + sw;
  const u16* dA2 = act + (size_t)(brow + 2 * 64 + rr) * ISZ + sw;
  const u16* dA3 = act + (size_t)(brow + 3 * 64 + rr) * ISZ + sw;
  const u16* dB0 = wdT + ((size_t)e * 1024 + bcol + 0 * 64 + rr) * ISZ + sw;
  const u16* dB1 = wdT + ((size_t)e * 1024 + bcol + 1 * 64 + rr) * ISZ + sw;
  const u16* dB2 = wdT + ((size_t)e * 1024 + bcol + 2 * 64 + rr) * ISZ + sw;
  const u16* dB3 = wdT + ((size_t)e * 1024 + bcol + 3 * 64 + rr) * ISZ + sw;

  const int aBase = (wm * 64 + fr) * 64;
  const int bBase = (wn * 128 + fr) * 64;
  const int kx0 = (fg ^ (fr & 7)) * 8;
  const int kx1 = kx0 ^ 32;

  f32x4 accf[4][8];
#pragma unroll
  for (int m = 0; m < 4; ++m)
#pragma unroll
    for (int n = 0; n < 8; ++n) accf[m][n] = (f32x4){0.f, 0.f, 0.f, 0.f};
  short8 gA[4], gB[8];

  const int NKT = ISZ / 64;   // 8 slots
  G2_STG(0);
  asm volatile("s_waitcnt vmcnt(0)" ::: "memory");
  __builtin_amdgcn_s_barrier();
  for (int s = 0; s < NKT; ++s) {
    const int rg = s & 1;
    if (s + 1 < NKT) G2_STG(s + 1);
    G2_LOADF(rg, kx0);
    asm volatile("s_waitcnt lgkmcnt(0)" ::: "memory");
    __builtin_amdgcn_sched_barrier(0);
    G2_MFMA;
    G2_LOADF(rg, kx1);
    asm volatile("s_waitcnt lgkmcnt(0)" ::: "memory");
    __builtin_amdgcn_sched_barrier(0);
    G2_MFMA;
    asm volatile("s_waitcnt vmcnt(0)" ::: "memory");
    __builtin_amdgcn_s_barrier();
  }

#pragma unroll
  for (int m = 0; m < 4; ++m) {
#pragma unroll
    for (int r = 0; r < 4; ++r) {
      const int row = brow + wm * 64 + m * 16 + fg * 4 + r;
#pragma unroll
      for (int n = 0; n < 8; ++n) {
        const int col = bcol + wn * 128 + n * 16 + fr;
        tmp[(size_t)row * HID + col] = f2bf(accf[m][n][r]);
      }
    }
  }
}

// ---------------- combine: out[t] = tmp[sh] + w0*tmp[s0] + w1*tmp[s1] -----------
__global__ __launch_bounds__(256) void k_combine(
    const u16* __restrict__ tmp, const int* __restrict__ slotmap,
    const float2* __restrict__ wts, float* __restrict__ out) {
  const int idx = blockIdx.x * 256 + threadIdx.x;
  const int t = idx >> 7;
  const int c = (idx & 127) << 3;
  const int s0 = slotmap[2 * t], s1 = slotmap[2 * t + 1];
  const float2 wv = wts[t];
  const short8 a = *(const short8*)(tmp + (size_t)s0 * HID + c);
  const short8 b = *(const short8*)(tmp + (size_t)s1 * HID + c);
  const short8 s = *(const short8*)(tmp + (size_t)(RBASE + t) * HID + c);
  float r[8];
#pragma unroll
  for (int j = 0; j < 8; ++j)
    r[j] = bf2f((u16)s[j]) + wv.x * bf2f((u16)a[j]) + wv.y * bf2f((u16)b[j]);
  float* po = out + (size_t)t * HID + c;
  *(float4*)po       = make_float4(r[0], r[1], r[2], r[3]);
  *(float4*)(po + 4) = make_float4(r[4], r[5], r[6], r[7]);
}

// ---------------- launch ----------------
extern "C" void kernel_launch(void* const* d_in, const int* in_sizes, int n_in,
                              void* d_out, int out_size, void* d_ws, size_t ws_size,
                              hipStream_t stream) {
  const float* x   = (const float*)d_in[0];
  const float* wg  = (const float*)d_in[1];
  const float* wgu = (const float*)d_in[2];
  const float* wdn = (const float*)d_in[3];
  const float* wsg = (const float*)d_in[4];
  const float* wsd = (const float*)d_in[5];
  float* out = (float*)d_out;

  char* ws = (char*)d_ws;
  i8*  xq    = (i8*)ws;   ws += (size_t)T_TOK * HID;
  i8*  wguq  = (i8*)ws;   ws += (size_t)NE * 1024 * HID;
  u16* wdT   = (u16*)ws;  ws += (size_t)NE * HID * ISZ * 2;
  u16* actb  = (u16*)ws;  ws += (size_t)NSLOT * ISZ * 2;
  u16* tmp   = (u16*)ws;  ws += (size_t)NSLOT * HID * 2;
  float* sxg = (float*)ws; ws += (size_t)T_TOK * 4;
  int* swc_i = (int*)ws;  ws += (size_t)NE * 1024 * 4;
  int* eidx  = (int*)ws;  ws += (size_t)T_TOK * 4;
  float2* wt = (float2*)ws; ws += (size_t)T_TOK * 8;
  int* btok  = (int*)ws;  ws += (size_t)RBASE * 4;
  int* smap  = (int*)ws;  ws += (size_t)2 * T_TOK * 4;
  int* seg   = (int*)ws;  ws += 16 * 4;
  int* segc  = (int*)ws;

  k_wamax<<<dim3(64, NE), 256, 0, stream>>>(wgu, wsg, swc_i);
  k_prep<<<NB_WGUP + NB_WDN + NB_RTR, 256, 0, stream>>>(
      x, wg, wgu, wsg, wdn, wsd, swc_i, xq, sxg, wguq, wdT, eidx, wt);
  k_scatter<<<1, 512, 0, stream>>>(eidx, btok, smap, seg, segc);
  k_gemm_gu<<<NROWB * 4, 512, 0, stream>>>(
      xq, wguq, seg, segc, btok, sxg, swc_i, actb);
  k_gemm_down<<<NROWB * 4, 512, 0, stream>>>(actb, wdT, seg, segc, tmp);
  k_combine<<<(T_TOK * HID / 8) / 256, 256, 0, stream>>>(tmp, smap, wt, out);
}

// Round 19
// 197.756 us; speedup vs baseline: 1.1234x; 1.0173x over previous
//
#include <hip/hip_runtime.h>
#include <hip/hip_bf16.h>
#include <cstdint>

#define T_TOK 8192
#define HID   1024
#define NE    9
#define ISZ   512
#define RBASE 18432
#define NSLOT (RBASE + T_TOK)   // 26624

#define BM 256
#define NROWB (NSLOT / BM)      // 104

typedef unsigned short u16;
typedef unsigned int   u32;
typedef signed char    i8;
typedef __attribute__((ext_vector_type(8))) short short8;
typedef __attribute__((ext_vector_type(4))) float f32x4;
typedef __attribute__((ext_vector_type(4))) int   i32x4;

__device__ __forceinline__ u16 f2bf(float f) {
  u32 u = __builtin_bit_cast(u32, f);
  return (u16)((u + 0x7fffu + ((u >> 16) & 1u)) >> 16);
}
__device__ __forceinline__ float bf2f(u16 v) {
  return __builtin_bit_cast(float, (u32)v << 16);
}
__device__ __forceinline__ int q8(float v, float inv) {
  int q = (int)__builtin_rintf(v * inv);
  return (q > 127) ? 127 : ((q < -127) ? -127 : q);
}
__device__ __forceinline__ int colp_of(int c) {
  int i = (c < 512) ? c : (c - 512);
  return (i >> 4) * 32 + ((c < 512) ? 0 : 16) + (i & 15);
}

#define STAGE(gp, lp) __builtin_amdgcn_global_load_lds( \
    (__attribute__((address_space(1))) u32*)(gp),       \
    (__attribute__((address_space(3))) u32*)(lp), 16, 0, 0)

// ---------------- k_rw: router (cold x) + per-column wamax (cold wgu), fused ----
// Both phases are latency-bound cold-HBM readers; co-residency doubles MLP.
#define NB_RTR  (T_TOK / 4)  // 2048
#define NB_WAM  (64 * NE)    // 576

__global__ __launch_bounds__(256) void k_rw(
    const float* __restrict__ x, const float* __restrict__ wg,
    const float* __restrict__ wgu, const float* __restrict__ wsg,
    i8* __restrict__ xq, float* __restrict__ sxg,
    int* __restrict__ eidx, float2* __restrict__ wts,
    int* __restrict__ swc_i) {
  const int b = blockIdx.x;
  const int tid = threadIdx.x;

  if (b >= NB_RTR) {
    // ---- wamax: block = 16 rows x 1024 cols of expert e; atomicMax (det.) ----
    const int flat = b - NB_RTR;
    const int e = flat >> 6, hb = flat & 63;
    const float* src = (e < 8) ? (wgu + (size_t)e * 1048576) : wsg;
    const int wv = tid >> 6, l = tid & 63;
    float4 m4[4];
#pragma unroll
    for (int j = 0; j < 4; ++j) m4[j] = make_float4(0.f, 0.f, 0.f, 0.f);
    const int r0 = hb * 16 + wv * 4;
#pragma unroll
    for (int r = 0; r < 4; ++r) {
      const float* row = src + (size_t)(r0 + r) * 1024;
#pragma unroll
      for (int j = 0; j < 4; ++j) {
        const float4 v = *(const float4*)&row[j * 256 + l * 4];
        m4[j].x = fmaxf(m4[j].x, fabsf(v.x));
        m4[j].y = fmaxf(m4[j].y, fabsf(v.y));
        m4[j].z = fmaxf(m4[j].z, fabsf(v.z));
        m4[j].w = fmaxf(m4[j].w, fabsf(v.w));
      }
    }
    __shared__ float4 red[4][4][64];
#pragma unroll
    for (int j = 0; j < 4; ++j) red[wv][j][l] = m4[j];
    __syncthreads();
    const int j2 = tid >> 6, l2 = tid & 63;
    const float4 a = red[0][j2][l2], bb = red[1][j2][l2];
    const float4 c = red[2][j2][l2], d = red[3][j2][l2];
    float o[4];
    o[0] = fmaxf(fmaxf(a.x, bb.x), fmaxf(c.x, d.x));
    o[1] = fmaxf(fmaxf(a.y, bb.y), fmaxf(c.y, d.y));
    o[2] = fmaxf(fmaxf(a.z, bb.z), fmaxf(c.z, d.z));
    o[3] = fmaxf(fmaxf(a.w, bb.w), fmaxf(c.w, d.w));
    const int cbase = j2 * 256 + l2 * 4;
#pragma unroll
    for (int k = 0; k < 4; ++k)
      atomicMax(&swc_i[e * 1024 + colp_of(cbase + k)], __float_as_int(o[k]));
    return;
  }

  // ---- router: 4 tokens/block; fused per-row amax quant of x ----
  const int t = b * 4 + (tid >> 6);
  const int l = tid & 63;
  float a[8] = {0, 0, 0, 0, 0, 0, 0, 0};
  float vals[16];
  float am = 0.f;
  const float4* xr4 = (const float4*)(x + (size_t)t * HID);
#pragma unroll
  for (int j = 0; j < 4; ++j) {
    const float4 v = xr4[j * 64 + l];
    vals[4 * j] = v.x; vals[4 * j + 1] = v.y; vals[4 * j + 2] = v.z; vals[4 * j + 3] = v.w;
    am = fmaxf(am, fmaxf(fmaxf(fabsf(v.x), fabsf(v.y)), fmaxf(fabsf(v.z), fabsf(v.w))));
    const int h = (j * 64 + l) * 4;
#pragma unroll
    for (int i = 0; i < 4; ++i) {
      const float4 w0 = *(const float4*)&wg[(h + i) * 8];
      const float4 w1 = *(const float4*)&wg[(h + i) * 8 + 4];
      const float ev = vals[4 * j + i];
      a[0] += ev * w0.x; a[1] += ev * w0.y; a[2] += ev * w0.z; a[3] += ev * w0.w;
      a[4] += ev * w1.x; a[5] += ev * w1.y; a[6] += ev * w1.z; a[7] += ev * w1.w;
    }
  }
#pragma unroll
  for (int off = 32; off >= 1; off >>= 1) {
    am = fmaxf(am, __shfl_xor(am, off));
#pragma unroll
    for (int e2 = 0; e2 < 8; ++e2) a[e2] += __shfl_xor(a[e2], off);
  }
  const float inv = (am > 0.f) ? 127.f / am : 0.f;
  u32* xq4 = (u32*)(xq + (size_t)t * HID);
#pragma unroll
  for (int j = 0; j < 4; ++j) {
    u32 q = ((u32)(unsigned char)(i8)q8(vals[4 * j], inv)) |
            ((u32)(unsigned char)(i8)q8(vals[4 * j + 1], inv) << 8) |
            ((u32)(unsigned char)(i8)q8(vals[4 * j + 2], inv) << 16) |
            ((u32)(unsigned char)(i8)q8(vals[4 * j + 3], inv) << 24);
    xq4[j * 64 + l] = q;
  }
  if (l == 0) {
    sxg[t] = am * (1.f / 127.f);
    int ia = 0;
#pragma unroll
    for (int e2 = 1; e2 < 8; ++e2) if (a[e2] > a[ia]) ia = e2;
    int ib = (ia == 0) ? 1 : 0;
#pragma unroll
    for (int e2 = 0; e2 < 8; ++e2) if (e2 != ia && a[e2] > a[ib]) ib = e2;
    float wa = 1.f / (1.f + expf(a[ib] - a[ia]));
    eidx[t] = ia | (ib << 8);
    wts[t] = make_float2(wa, 1.f - wa);
  }
}

// ---------------- k_prep2: wide-tile weight transposes only ----------------
#define NB_WGUP (128 * NE)   // 1152
#define NB_WDN  (64 * NE)    // 576

__global__ __launch_bounds__(256) void k_prep2(
    const float* __restrict__ wgu, const float* __restrict__ wsg,
    const float* __restrict__ wdn, const float* __restrict__ wsd,
    const int* __restrict__ swc_i,
    i8* __restrict__ wguq, u16* __restrict__ wdT) {
  __shared__ float tile[64][130];
  const int b = blockIdx.x;
  const int tid = threadIdx.x;

  if (b < NB_WGUP) {
    const int e = b / 128, rem = b % 128;
    const int c0 = (rem & 15) * 64, h0 = (rem >> 4) * 128;
    const float* src = (e < 8) ? (wgu + (size_t)e * HID * 1024) : wsg;
    const int hl = tid >> 1, cb = (tid & 1) * 32;
    float4 v[8];
#pragma unroll
    for (int j = 0; j < 8; ++j)
      v[j] = *(const float4*)&src[(size_t)(h0 + hl) * 1024 + c0 + cb + j * 4];
#pragma unroll
    for (int j = 0; j < 8; ++j) {
      tile[cb + j * 4 + 0][hl] = v[j].x;
      tile[cb + j * 4 + 1][hl] = v[j].y;
      tile[cb + j * 4 + 2][hl] = v[j].z;
      tile[cb + j * 4 + 3][hl] = v[j].w;
    }
    __syncthreads();
    const int cl = tid >> 2, hb = (tid & 3) * 32;
    const int cp = colp_of(c0 + cl);
    const float inv = 127.f / __int_as_float(swc_i[e * 1024 + cp]);
    i8 out[32];
#pragma unroll
    for (int k = 0; k < 32; ++k) out[k] = (i8)q8(tile[cl][hb + k], inv);
    i8* dst = &wguq[((size_t)e * 1024 + cp) * 1024 + h0 + hb];
    *(int4*)dst = *(int4*)out;
    *(int4*)(dst + 16) = *(int4*)(out + 16);
    return;
  }
  const int bb = b - NB_WGUP;
  const int e = bb / 64, rem = bb % 64;
  const int h0 = (rem & 15) * 64, i0 = (rem >> 4) * 128;
  const float* src = (e < 8) ? (wdn + (size_t)e * ISZ * HID) : wsd;
  const int il = tid >> 1, hb = (tid & 1) * 32;
  float4 v[8];
#pragma unroll
  for (int j = 0; j < 8; ++j)
    v[j] = *(const float4*)&src[(size_t)(i0 + il) * 1024 + h0 + hb + j * 4];
#pragma unroll
  for (int j = 0; j < 8; ++j) {
    tile[hb + j * 4 + 0][il] = v[j].x;
    tile[hb + j * 4 + 1][il] = v[j].y;
    tile[hb + j * 4 + 2][il] = v[j].z;
    tile[hb + j * 4 + 3][il] = v[j].w;
  }
  __syncthreads();
  const int hl = tid >> 2, ib = (tid & 3) * 32;
  u16 ob[32];
#pragma unroll
  for (int k = 0; k < 32; ++k) ob[k] = f2bf(tile[hl][ib + k]);
  u16* dst = &wdT[((size_t)e * HID + h0 + hl) * ISZ + i0 + ib];
  *(int4*)dst        = *(int4*)ob;
  *(int4*)(dst + 8)  = *(int4*)(ob + 8);
  *(int4*)(dst + 16) = *(int4*)(ob + 16);
  *(int4*)(dst + 24) = *(int4*)(ob + 24);
}

// ---------------- deterministic counting scatter (256-aligned segments) --------
__global__ __launch_bounds__(512) void k_scatter(
    const int* __restrict__ eidx, int* __restrict__ btok, int* __restrict__ slotmap,
    int* __restrict__ seg, int* __restrict__ segcnt) {
  __shared__ int cnt_s[8];
  __shared__ int goff_s[9];
  const int e = threadIdx.x >> 6;
  const int l = threadIdx.x & 63;

  int c1 = 0;
  for (int c = 0; c < T_TOK / 64; ++c) {
    int v = eidx[c * 64 + l];
    c1 += __popcll(__ballot((v & 255) == e)) + __popcll(__ballot(((v >> 8) & 255) == e));
  }
  if (l == 0) cnt_s[e] = c1;
  __syncthreads();
  if (threadIdx.x == 0) {
    int off = 0;
    for (int k = 0; k < 8; ++k) { goff_s[k] = off; off += (cnt_s[k] + 255) & ~255; }
    goff_s[8] = off;
  }
  __syncthreads();
  const int base0 = goff_s[e];
  const int cnt_e = cnt_s[e];
  const unsigned long long below = (l == 63) ? ~0ull >> 1 : ((1ull << l) - 1);

  int base = base0;
  for (int c = 0; c < T_TOK / 64; ++c) {
    const int t = c * 64 + l;
    const int v = eidx[t];
    const unsigned long long ma = __ballot((v & 255) == e);
    const unsigned long long mb = __ballot(((v >> 8) & 255) == e);
    if ((v & 255) == e) {
      int s = base + __popcll(ma & below);
      btok[s] = t; slotmap[2 * t] = s;
    }
    if (((v >> 8) & 255) == e) {
      int s = base + __popcll(ma) + __popcll(mb & below);
      btok[s] = t; slotmap[2 * t + 1] = s;
    }
    base += __popcll(ma) + __popcll(mb);
  }
  for (int p = cnt_e + l; p < ((cnt_e + 255) & ~255); p += 64) btok[base0 + p] = 0;
  if (threadIdx.x < 9) seg[threadIdx.x] = goff_s[threadIdx.x];
  if (threadIdx.x < 8) segcnt[threadIdx.x] = cnt_s[threadIdx.x];
}

__device__ __forceinline__ bool seg_lookup(const int* __restrict__ seg,
                                           const int* __restrict__ segcnt,
                                           int brow, int& e) {
  if (brow >= RBASE) { e = 8; return true; }
  if (brow >= seg[8]) return false;
  e = 0;
#pragma unroll
  for (int k = 1; k < 8; ++k) if (brow >= seg[k]) e = k;
  return brow < seg[e] + segcnt[e];
}

// =================================================================================
// GEMM1 (int8): 256x256 tile, K-slot=128 i8, 8 waves 4M x 2N (per-wave 64x128).
// LDS: 2-ring A + 2-ring B = 128KB. Depth-1 stage-ahead, ^(row&7) swizzle.
// =================================================================================

#define G1_STG(kt) do { const int _r = ((kt) & 1) * 32768;          \
    STAGE(sA0 + (kt) * 128, Ab + _r + 0 * 8192 + w * 1024);         \
    STAGE(sA1 + (kt) * 128, Ab + _r + 1 * 8192 + w * 1024);         \
    STAGE(sA2 + (kt) * 128, Ab + _r + 2 * 8192 + w * 1024);         \
    STAGE(sA3 + (kt) * 128, Ab + _r + 3 * 8192 + w * 1024);         \
    STAGE(sB0 + (kt) * 128, Bb + _r + 0 * 8192 + w * 1024);         \
    STAGE(sB1 + (kt) * 128, Bb + _r + 1 * 8192 + w * 1024);         \
    STAGE(sB2 + (kt) * 128, Bb + _r + 2 * 8192 + w * 1024);         \
    STAGE(sB3 + (kt) * 128, Bb + _r + 3 * 8192 + w * 1024); } while (0)

#define G1_LOADF(RG, KX) do {                                       \
    _Pragma("unroll") for (int m = 0; m < 4; ++m)                   \
      fA[m] = *(const i32x4*)&Ab[(RG) * 32768 + aBase + m * 2048 + (KX)]; \
    _Pragma("unroll") for (int n = 0; n < 8; ++n)                   \
      fB[n] = *(const i32x4*)&Bb[(RG) * 32768 + bBase + n * 2048 + (KX)]; } while (0)

#define G1_MFMA do { __builtin_amdgcn_s_setprio(1);                 \
    _Pragma("unroll") for (int m = 0; m < 4; ++m)                   \
      _Pragma("unroll") for (int n = 0; n < 8; ++n)                 \
        acc[m][n] = __builtin_amdgcn_mfma_i32_16x16x64_i8(fA[m], fB[n], acc[m][n], 0, 0, 0); \
    __builtin_amdgcn_s_setprio(0); } while (0)

__global__ __launch_bounds__(512) void k_gemm_gu(
    const i8* __restrict__ xq, const i8* __restrict__ wguq,
    const int* __restrict__ seg, const int* __restrict__ segcnt,
    const int* __restrict__ btok, const float* __restrict__ sxg,
    const int* __restrict__ swc_i,
    u16* __restrict__ act)
{
  const int bid = blockIdx.x;
  const int brow = (bid % NROWB) * BM;
  const int bcol = (bid / NROWB) * 256;
  int e;
  if (!seg_lookup(seg, segcnt, brow, e)) return;

  __shared__ __align__(16) i8 Ab[2 * 32768];
  __shared__ __align__(16) i8 Bb[2 * 32768];
  __shared__ float sxl[BM];
  __shared__ float swcl[256];

  const int tid = threadIdx.x;
  const int w = tid >> 6, l = tid & 63;
  const int wm = w >> 1, wn = w & 1;
  const int fr = l & 15, fg = l >> 4;

  if (tid < BM) {
    const int rrow = brow + tid;
    const int tk = (e < 8) ? btok[rrow] : (rrow - RBASE);
    sxl[tid] = sxg[tk];
  } else {
    swcl[tid - 256] = __int_as_float(swc_i[e * 1024 + bcol + (tid - 256)]) * (1.f / 127.f);
  }

  const int rr = w * 8 + (l >> 3);
  const int sw = ((l & 7) ^ (l >> 3)) * 16;
  int tr[4];
#pragma unroll
  for (int j = 0; j < 4; ++j) {
    const int gr = brow + j * 64 + rr;
    tr[j] = (e < 8) ? btok[gr] : (gr - RBASE);
  }
  const i8* sA0 = xq + (size_t)tr[0] * HID + sw;
  const i8* sA1 = xq + (size_t)tr[1] * HID + sw;
  const i8* sA2 = xq + (size_t)tr[2] * HID + sw;
  const i8* sA3 = xq + (size_t)tr[3] * HID + sw;
  const i8* sB0 = wguq + ((size_t)e * 1024 + bcol + 0 * 64 + rr) * HID + sw;
  const i8* sB1 = wguq + ((size_t)e * 1024 + bcol + 1 * 64 + rr) * HID + sw;
  const i8* sB2 = wguq + ((size_t)e * 1024 + bcol + 2 * 64 + rr) * HID + sw;
  const i8* sB3 = wguq + ((size_t)e * 1024 + bcol + 3 * 64 + rr) * HID + sw;

  const int aBase = (wm * 64 + fr) * 128;
  const int bBase = (wn * 128 + fr) * 128;
  const int kx0 = (fg ^ (fr & 7)) * 16;
  const int kx1 = kx0 ^ 64;

  i32x4 acc[4][8];
#pragma unroll
  for (int m = 0; m < 4; ++m)
#pragma unroll
    for (int n = 0; n < 8; ++n) acc[m][n] = (i32x4){0, 0, 0, 0};
  i32x4 fA[4], fB[8];

  const int NKT = HID / 128;
  G1_STG(0);
  asm volatile("s_waitcnt vmcnt(0)" ::: "memory");
  __builtin_amdgcn_s_barrier();
  for (int s = 0; s < NKT; ++s) {
    const int rg = s & 1;
    if (s + 1 < NKT) G1_STG(s + 1);
    G1_LOADF(rg, kx0);
    asm volatile("s_waitcnt lgkmcnt(0)" ::: "memory");
    __builtin_amdgcn_sched_barrier(0);
    G1_MFMA;
    G1_LOADF(rg, kx1);
    asm volatile("s_waitcnt lgkmcnt(0)" ::: "memory");
    __builtin_amdgcn_sched_barrier(0);
    G1_MFMA;
    asm volatile("s_waitcnt vmcnt(0)" ::: "memory");
    __builtin_amdgcn_s_barrier();
  }

#pragma unroll
  for (int m = 0; m < 4; ++m) {
#pragma unroll
    for (int p = 0; p < 4; ++p) {
      const i32x4 gI = acc[m][2 * p], uI = acc[m][2 * p + 1];
      const int col = ((bcol + wn * 128) >> 1) + p * 16 + fr;
      const float swg = swcl[wn * 128 + p * 32 + fr];
      const float swu = swcl[wn * 128 + p * 32 + 16 + fr];
#pragma unroll
      for (int r = 0; r < 4; ++r) {
        const int row_l = wm * 64 + m * 16 + fg * 4 + r;
        const float sx = sxl[row_l];
        const float gate = (float)gI[r] * (sx * swg);
        const float up   = (float)uI[r] * (sx * swu);
        const float sv = gate / (1.f + __expf(-gate));
        act[(size_t)(brow + row_l) * ISZ + col] = f2bf(sv * up);
      }
    }
  }
}

// =================================================================================
// GEMM2 (bf16): mirror of GEMM1. K-slot=64 bf16, 2-ring LDS, ^(row&7) swizzle.
// =================================================================================

#define G2_STG(kt) do { const int _r = ((kt) & 1) * 16384;          \
    STAGE(dA0 + (kt) * 64, As2 + _r + 0 * 4096 + w * 512);          \
    STAGE(dA1 + (kt) * 64, As2 + _r + 1 * 4096 + w * 512);          \
    STAGE(dA2 + (kt) * 64, As2 + _r + 2 * 4096 + w * 512);          \
    STAGE(dA3 + (kt) * 64, As2 + _r + 3 * 4096 + w * 512);          \
    STAGE(dB0 + (kt) * 64, Bs2 + _r + 0 * 4096 + w * 512);          \
    STAGE(dB1 + (kt) * 64, Bs2 + _r + 1 * 4096 + w * 512);          \
    STAGE(dB2 + (kt) * 64, Bs2 + _r + 2 * 4096 + w * 512);          \
    STAGE(dB3 + (kt) * 64, Bs2 + _r + 3 * 4096 + w * 512); } while (0)

#define G2_LOADF(RG, KX) do {                                       \
    _Pragma("unroll") for (int m = 0; m < 4; ++m)                   \
      gA[m] = *(const short8*)&As2[(RG) * 16384 + aBase + m * 1024 + (KX)]; \
    _Pragma("unroll") for (int n = 0; n < 8; ++n)                   \
      gB[n] = *(const short8*)&Bs2[(RG) * 16384 + bBase + n * 1024 + (KX)]; } while (0)

#define G2_MFMA do { __builtin_amdgcn_s_setprio(1);                 \
    _Pragma("unroll") for (int m = 0; m < 4; ++m)                   \
      _Pragma("unroll") for (int n = 0; n < 8; ++n)                 \
        accf[m][n] = __builtin_amdgcn_mfma_f32_16x16x32_bf16(gA[m], gB[n], accf[m][n], 0, 0, 0); \
    __builtin_amdgcn_s_setprio(0); } while (0)

__global__ __launch_bounds__(512) void k_gemm_down(
    const u16* __restrict__ act, const u16* __restrict__ wdT,
    const int* __restrict__ seg, const int* __restrict__ segcnt,
    u16* __restrict__ tmp) {
  const int bid = blockIdx.x;
  const int brow = (bid % NROWB) * BM;
  const int bcol = (bid / NROWB) * 256;
  int e;
  if (!seg_lookup(seg, segcnt, brow, e)) return;

  __shared__ __align__(16) u16 As2[2 * 16384];
  __shared__ __align__(16) u16 Bs2[2 * 16384];

  const int tid = threadIdx.x;
  const int w = tid >> 6, l = tid & 63;
  const int wm = w >> 1, wn = w & 1;
  const int fr = l & 15, fg = l >> 4;

  const int rr = w * 8 + (l >> 3);
  const int sw = ((l & 7) ^ (l >> 3)) * 8;
  const u16* dA0 = act + (size_t)(brow + 0 * 64 + rr) * ISZ + sw;
  const u16* dA1 = act + (size_t)(brow + 1 * 64 + rr) * ISZ + sw;
  const u16* dA2 = act + (size_t)(brow + 2 * 64 + rr) * ISZ + sw;
  const u16* dA3 = act + (size_t)(brow + 3 * 64 + rr) * ISZ + sw;
  const u16* dB0 = wdT + ((size_t)e * 1024 + bcol + 0 * 64 + rr) * ISZ + sw;
  const u16* dB1 = wdT + ((size_t)e * 1024 + bcol + 1 * 64 + rr) * ISZ + sw;
  const u16* dB2 = wdT + ((size_t)e * 1024 + bcol + 2 * 64 + rr) * ISZ + sw;
  const u16* dB3 = wdT + ((size_t)e * 1024 + bcol + 3 * 64 + rr) * ISZ + sw;

  const int aBase = (wm * 64 + fr) * 64;
  const int bBase = (wn * 128 + fr) * 64;
  const int kx0 = (fg ^ (fr & 7)) * 8;
  const int kx1 = kx0 ^ 32;

  f32x4 accf[4][8];
#pragma unroll
  for (int m = 0; m < 4; ++m)
#pragma unroll
    for (int n = 0; n < 8; ++n) accf[m][n] = (f32x4){0.f, 0.f, 0.f, 0.f};
  short8 gA[4], gB[8];

  const int NKT = ISZ / 64;
  G2_STG(0);
  asm volatile("s_waitcnt vmcnt(0)" ::: "memory");
  __builtin_amdgcn_s_barrier();
  for (int s = 0; s < NKT; ++s) {
    const int rg = s & 1;
    if (s + 1 < NKT) G2_STG(s + 1);
    G2_LOADF(rg, kx0);
    asm volatile("s_waitcnt lgkmcnt(0)" ::: "memory");
    __builtin_amdgcn_sched_barrier(0);
    G2_MFMA;
    G2_LOADF(rg, kx1);
    asm volatile("s_waitcnt lgkmcnt(0)" ::: "memory");
    __builtin_amdgcn_sched_barrier(0);
    G2_MFMA;
    asm volatile("s_waitcnt vmcnt(0)" ::: "memory");
    __builtin_amdgcn_s_barrier();
  }

#pragma unroll
  for (int m = 0; m < 4; ++m) {
#pragma unroll
    for (int r = 0; r < 4; ++r) {
      const int row = brow + wm * 64 + m * 16 + fg * 4 + r;
#pragma unroll
      for (int n = 0; n < 8; ++n) {
        const int col = bcol + wn * 128 + n * 16 + fr;
        tmp[(size_t)row * HID + col] = f2bf(accf[m][n][r]);
      }
    }
  }
}

// ---------------- combine: out[t] = tmp[sh] + w0*tmp[s0] + w1*tmp[s1] -----------
__global__ __launch_bounds__(256) void k_combine(
    const u16* __restrict__ tmp, const int* __restrict__ slotmap,
    const float2* __restrict__ wts, float* __restrict__ out) {
  const int idx = blockIdx.x * 256 + threadIdx.x;
  const int t = idx >> 7;
  const int c = (idx & 127) << 3;
  const int s0 = slotmap[2 * t], s1 = slotmap[2 * t + 1];
  const float2 wv = wts[t];
  const short8 a = *(const short8*)(tmp + (size_t)s0 * HID + c);
  const short8 b = *(const short8*)(tmp + (size_t)s1 * HID + c);
  const short8 s = *(const short8*)(tmp + (size_t)(RBASE + t) * HID + c);
  float r[8];
#pragma unroll
  for (int j = 0; j < 8; ++j)
    r[j] = bf2f((u16)s[j]) + wv.x * bf2f((u16)a[j]) + wv.y * bf2f((u16)b[j]);
  float* po = out + (size_t)t * HID + c;
  *(float4*)po       = make_float4(r[0], r[1], r[2], r[3]);
  *(float4*)(po + 4) = make_float4(r[4], r[5], r[6], r[7]);
}

// ---------------- launch ----------------
extern "C" void kernel_launch(void* const* d_in, const int* in_sizes, int n_in,
                              void* d_out, int out_size, void* d_ws, size_t ws_size,
                              hipStream_t stream) {
  const float* x   = (const float*)d_in[0];
  const float* wg  = (const float*)d_in[1];
  const float* wgu = (const float*)d_in[2];
  const float* wdn = (const float*)d_in[3];
  const float* wsg = (const float*)d_in[4];
  const float* wsd = (const float*)d_in[5];
  float* out = (float*)d_out;

  char* ws = (char*)d_ws;
  i8*  xq    = (i8*)ws;   ws += (size_t)T_TOK * HID;
  i8*  wguq  = (i8*)ws;   ws += (size_t)NE * 1024 * HID;
  u16* wdT   = (u16*)ws;  ws += (size_t)NE * HID * ISZ * 2;
  u16* actb  = (u16*)ws;  ws += (size_t)NSLOT * ISZ * 2;
  u16* tmp   = (u16*)ws;  ws += (size_t)NSLOT * HID * 2;
  float* sxg = (float*)ws; ws += (size_t)T_TOK * 4;
  int* swc_i = (int*)ws;  ws += (size_t)NE * 1024 * 4;
  int* eidx  = (int*)ws;  ws += (size_t)T_TOK * 4;
  float2* wt = (float2*)ws; ws += (size_t)T_TOK * 8;
  int* btok  = (int*)ws;  ws += (size_t)RBASE * 4;
  int* smap  = (int*)ws;  ws += (size_t)2 * T_TOK * 4;
  int* seg   = (int*)ws;  ws += 16 * 4;
  int* segc  = (int*)ws;

  k_rw<<<NB_RTR + NB_WAM, 256, 0, stream>>>(
      x, wg, wgu, wsg, xq, sxg, eidx, wt, swc_i);
  k_prep2<<<NB_WGUP + NB_WDN, 256, 0, stream>>>(
      wgu, wsg, wdn, wsd, swc_i, wguq, wdT);
  k_scatter<<<1, 512, 0, stream>>>(eidx, btok, smap, seg, segc);
  k_gemm_gu<<<NROWB * 4, 512, 0, stream>>>(
      xq, wguq, seg, segc, btok, sxg, swc_i, actb);
  k_gemm_down<<<NROWB * 4, 512, 0, stream>>>(actb, wdT, seg, segc, tmp);
  k_combine<<<(T_TOK * HID / 8) / 256, 256, 0, stream>>>(tmp, smap, wt, out);
}

// Round 20
// 180.513 us; speedup vs baseline: 1.2307x; 1.0955x over previous
//
#include <hip/hip_runtime.h>
#include <hip/hip_bf16.h>
#include <cstdint>

#define T_TOK 8192
#define HID   1024
#define NE    9
#define ISZ   512
#define RBASE 18432
#define NSLOT (RBASE + T_TOK)   // 26624

#define BM 256
#define NROWB (NSLOT / BM)      // 104

typedef unsigned short u16;
typedef unsigned int   u32;
typedef signed char    i8;
typedef __attribute__((ext_vector_type(8))) short short8;
typedef __attribute__((ext_vector_type(4))) float f32x4;
typedef __attribute__((ext_vector_type(4))) int   i32x4;

__device__ __forceinline__ u16 f2bf(float f) {
  u32 u = __builtin_bit_cast(u32, f);
  return (u16)((u + 0x7fffu + ((u >> 16) & 1u)) >> 16);
}
__device__ __forceinline__ float bf2f(u16 v) {
  return __builtin_bit_cast(float, (u32)v << 16);
}
__device__ __forceinline__ int q8(float v, float inv) {
  int q = (int)__builtin_rintf(v * inv);
  return (q > 127) ? 127 : ((q < -127) ? -127 : q);
}
__device__ __forceinline__ int colp_of(int c) {
  int i = (c < 512) ? c : (c - 512);
  return (i >> 4) * 32 + ((c < 512) ? 0 : 16) + (i & 15);
}

#define STAGE(gp, lp) __builtin_amdgcn_global_load_lds( \
    (__attribute__((address_space(1))) u32*)(gp),       \
    (__attribute__((address_space(3))) u32*)(lp), 16, 0, 0)

// ---------------- k_rw: router (cold x) + per-column wamax (cold wgu), fused ----
#define NB_RTR  (T_TOK / 4)  // 2048
#define NB_WAM  (64 * NE)    // 576

__global__ __launch_bounds__(256) void k_rw(
    const float* __restrict__ x, const float* __restrict__ wg,
    const float* __restrict__ wgu, const float* __restrict__ wsg,
    i8* __restrict__ xq, float* __restrict__ sxg,
    int* __restrict__ eidx, float2* __restrict__ wts,
    int* __restrict__ swc_i) {
  const int b = blockIdx.x;
  const int tid = threadIdx.x;

  if (b >= NB_RTR) {
    // ---- wamax: block = 16 rows x 1024 cols of expert e; atomicMax (det.) ----
    const int flat = b - NB_RTR;
    const int e = flat >> 6, hb = flat & 63;
    const float* src = (e < 8) ? (wgu + (size_t)e * 1048576) : wsg;
    const int wv = tid >> 6, l = tid & 63;
    float4 m4[4];
#pragma unroll
    for (int j = 0; j < 4; ++j) m4[j] = make_float4(0.f, 0.f, 0.f, 0.f);
    const int r0 = hb * 16 + wv * 4;
#pragma unroll
    for (int r = 0; r < 4; ++r) {
      const float* row = src + (size_t)(r0 + r) * 1024;
#pragma unroll
      for (int j = 0; j < 4; ++j) {
        const float4 v = *(const float4*)&row[j * 256 + l * 4];
        m4[j].x = fmaxf(m4[j].x, fabsf(v.x));
        m4[j].y = fmaxf(m4[j].y, fabsf(v.y));
        m4[j].z = fmaxf(m4[j].z, fabsf(v.z));
        m4[j].w = fmaxf(m4[j].w, fabsf(v.w));
      }
    }
    __shared__ float4 red[4][4][64];
#pragma unroll
    for (int j = 0; j < 4; ++j) red[wv][j][l] = m4[j];
    __syncthreads();
    const int j2 = tid >> 6, l2 = tid & 63;
    const float4 a = red[0][j2][l2], bb = red[1][j2][l2];
    const float4 c = red[2][j2][l2], d = red[3][j2][l2];
    float o[4];
    o[0] = fmaxf(fmaxf(a.x, bb.x), fmaxf(c.x, d.x));
    o[1] = fmaxf(fmaxf(a.y, bb.y), fmaxf(c.y, d.y));
    o[2] = fmaxf(fmaxf(a.z, bb.z), fmaxf(c.z, d.z));
    o[3] = fmaxf(fmaxf(a.w, bb.w), fmaxf(c.w, d.w));
    const int cbase = j2 * 256 + l2 * 4;
#pragma unroll
    for (int k = 0; k < 4; ++k)
      atomicMax(&swc_i[e * 1024 + colp_of(cbase + k)], __float_as_int(o[k]));
    return;
  }

  // ---- router: 4 tokens/block, 1 wave/token; COALESCED wg rows (h = j*64+l) ----
  const int t = b * 4 + (tid >> 6);
  const int l = tid & 63;
  float a[8] = {0, 0, 0, 0, 0, 0, 0, 0};
  float vals[16];
  float am = 0.f;
  const float* xr = x + (size_t)t * HID;
#pragma unroll
  for (int j = 0; j < 16; ++j) {
    const int h = j * 64 + l;
    const float xv = xr[h];                       // 256B/wave coalesced
    vals[j] = xv;
    am = fmaxf(am, fabsf(xv));
    const float4 w0 = *(const float4*)&wg[h * 8]; // 32B/lane contiguous rows
    const float4 w1 = *(const float4*)&wg[h * 8 + 4];
    a[0] += xv * w0.x; a[1] += xv * w0.y; a[2] += xv * w0.z; a[3] += xv * w0.w;
    a[4] += xv * w1.x; a[5] += xv * w1.y; a[6] += xv * w1.z; a[7] += xv * w1.w;
  }
#pragma unroll
  for (int off = 32; off >= 1; off >>= 1) {
    am = fmaxf(am, __shfl_xor(am, off));
#pragma unroll
    for (int e2 = 0; e2 < 8; ++e2) a[e2] += __shfl_xor(a[e2], off);
  }
  const float inv = (am > 0.f) ? 127.f / am : 0.f;
  i8* xqr = xq + (size_t)t * HID;
#pragma unroll
  for (int j = 0; j < 16; ++j)
    xqr[j * 64 + l] = (i8)q8(vals[j], inv);       // 64B/wave coalesced
  if (l == 0) {
    sxg[t] = am * (1.f / 127.f);
    int ia = 0;
#pragma unroll
    for (int e2 = 1; e2 < 8; ++e2) if (a[e2] > a[ia]) ia = e2;
    int ib = (ia == 0) ? 1 : 0;
#pragma unroll
    for (int e2 = 0; e2 < 8; ++e2) if (e2 != ia && a[e2] > a[ib]) ib = e2;
    float wa = 1.f / (1.f + expf(a[ib] - a[ia]));
    eidx[t] = ia | (ib << 8);
    wts[t] = make_float2(wa, 1.f - wa);
  }
}

// ---------------- k_prep2: wide-tile weight transposes only ----------------
#define NB_WGUP (128 * NE)   // 1152
#define NB_WDN  (64 * NE)    // 576

__global__ __launch_bounds__(256) void k_prep2(
    const float* __restrict__ wgu, const float* __restrict__ wsg,
    const float* __restrict__ wdn, const float* __restrict__ wsd,
    const int* __restrict__ swc_i,
    i8* __restrict__ wguq, u16* __restrict__ wdT) {
  __shared__ float tile[64][130];
  const int b = blockIdx.x;
  const int tid = threadIdx.x;

  if (b < NB_WGUP) {
    const int e = b / 128, rem = b % 128;
    const int c0 = (rem & 15) * 64, h0 = (rem >> 4) * 128;
    const float* src = (e < 8) ? (wgu + (size_t)e * HID * 1024) : wsg;
    const int hl = tid >> 1, cb = (tid & 1) * 32;
    float4 v[8];
#pragma unroll
    for (int j = 0; j < 8; ++j)
      v[j] = *(const float4*)&src[(size_t)(h0 + hl) * 1024 + c0 + cb + j * 4];
#pragma unroll
    for (int j = 0; j < 8; ++j) {
      tile[cb + j * 4 + 0][hl] = v[j].x;
      tile[cb + j * 4 + 1][hl] = v[j].y;
      tile[cb + j * 4 + 2][hl] = v[j].z;
      tile[cb + j * 4 + 3][hl] = v[j].w;
    }
    __syncthreads();
    const int cl = tid >> 2, hb = (tid & 3) * 32;
    const int cp = colp_of(c0 + cl);
    const float inv = 127.f / __int_as_float(swc_i[e * 1024 + cp]);
    i8 out[32];
#pragma unroll
    for (int k = 0; k < 32; ++k) out[k] = (i8)q8(tile[cl][hb + k], inv);
    i8* dst = &wguq[((size_t)e * 1024 + cp) * 1024 + h0 + hb];
    *(int4*)dst = *(int4*)out;
    *(int4*)(dst + 16) = *(int4*)(out + 16);
    return;
  }
  const int bb = b - NB_WGUP;
  const int e = bb / 64, rem = bb % 64;
  const int h0 = (rem & 15) * 64, i0 = (rem >> 4) * 128;
  const float* src = (e < 8) ? (wdn + (size_t)e * ISZ * HID) : wsd;
  const int il = tid >> 1, hb = (tid & 1) * 32;
  float4 v[8];
#pragma unroll
  for (int j = 0; j < 8; ++j)
    v[j] = *(const float4*)&src[(size_t)(i0 + il) * 1024 + h0 + hb + j * 4];
#pragma unroll
  for (int j = 0; j < 8; ++j) {
    tile[hb + j * 4 + 0][il] = v[j].x;
    tile[hb + j * 4 + 1][il] = v[j].y;
    tile[hb + j * 4 + 2][il] = v[j].z;
    tile[hb + j * 4 + 3][il] = v[j].w;
  }
  __syncthreads();
  const int hl = tid >> 2, ib = (tid & 3) * 32;
  u16 ob[32];
#pragma unroll
  for (int k = 0; k < 32; ++k) ob[k] = f2bf(tile[hl][ib + k]);
  u16* dst = &wdT[((size_t)e * HID + h0 + hl) * ISZ + i0 + ib];
  *(int4*)dst        = *(int4*)ob;
  *(int4*)(dst + 8)  = *(int4*)(ob + 8);
  *(int4*)(dst + 16) = *(int4*)(ob + 16);
  *(int4*)(dst + 24) = *(int4*)(ob + 24);
}

// ---------------- deterministic counting scatter (256-aligned segments) --------
__global__ __launch_bounds__(512) void k_scatter(
    const int* __restrict__ eidx, int* __restrict__ btok, int* __restrict__ slotmap,
    int* __restrict__ seg, int* __restrict__ segcnt) {
  __shared__ int cnt_s[8];
  __shared__ int goff_s[9];
  const int e = threadIdx.x >> 6;
  const int l = threadIdx.x & 63;

  int c1 = 0;
  for (int c = 0; c < T_TOK / 64; ++c) {
    int v = eidx[c * 64 + l];
    c1 += __popcll(__ballot((v & 255) == e)) + __popcll(__ballot(((v >> 8) & 255) == e));
  }
  if (l == 0) cnt_s[e] = c1;
  __syncthreads();
  if (threadIdx.x == 0) {
    int off = 0;
    for (int k = 0; k < 8; ++k) { goff_s[k] = off; off += (cnt_s[k] + 255) & ~255; }
    goff_s[8] = off;
  }
  __syncthreads();
  const int base0 = goff_s[e];
  const int cnt_e = cnt_s[e];
  const unsigned long long below = (l == 63) ? ~0ull >> 1 : ((1ull << l) - 1);

  int base = base0;
  for (int c = 0; c < T_TOK / 64; ++c) {
    const int t = c * 64 + l;
    const int v = eidx[t];
    const unsigned long long ma = __ballot((v & 255) == e);
    const unsigned long long mb = __ballot(((v >> 8) & 255) == e);
    if ((v & 255) == e) {
      int s = base + __popcll(ma & below);
      btok[s] = t; slotmap[2 * t] = s;
    }
    if (((v >> 8) & 255) == e) {
      int s = base + __popcll(ma) + __popcll(mb & below);
      btok[s] = t; slotmap[2 * t + 1] = s;
    }
    base += __popcll(ma) + __popcll(mb);
  }
  for (int p = cnt_e + l; p < ((cnt_e + 255) & ~255); p += 64) btok[base0 + p] = 0;
  if (threadIdx.x < 9) seg[threadIdx.x] = goff_s[threadIdx.x];
  if (threadIdx.x < 8) segcnt[threadIdx.x] = cnt_s[threadIdx.x];
}

__device__ __forceinline__ bool seg_lookup(const int* __restrict__ seg,
                                           const int* __restrict__ segcnt,
                                           int brow, int& e) {
  if (brow >= RBASE) { e = 8; return true; }
  if (brow >= seg[8]) return false;
  e = 0;
#pragma unroll
  for (int k = 1; k < 8; ++k) if (brow >= seg[k]) e = k;
  return brow < seg[e] + segcnt[e];
}

// =================================================================================
// GEMM1 (int8): 256x256 tile, K-slot=128 i8, 8 waves 4M x 2N (per-wave 64x128).
// LDS: 2-ring A + 2-ring B = 128KB. Depth-1 stage-ahead, ^(row&7) swizzle.
// =================================================================================

#define G1_STG(kt) do { const int _r = ((kt) & 1) * 32768;          \
    STAGE(sA0 + (kt) * 128, Ab + _r + 0 * 8192 + w * 1024);         \
    STAGE(sA1 + (kt) * 128, Ab + _r + 1 * 8192 + w * 1024);         \
    STAGE(sA2 + (kt) * 128, Ab + _r + 2 * 8192 + w * 1024);         \
    STAGE(sA3 + (kt) * 128, Ab + _r + 3 * 8192 + w * 1024);         \
    STAGE(sB0 + (kt) * 128, Bb + _r + 0 * 8192 + w * 1024);         \
    STAGE(sB1 + (kt) * 128, Bb + _r + 1 * 8192 + w * 1024);         \
    STAGE(sB2 + (kt) * 128, Bb + _r + 2 * 8192 + w * 1024);         \
    STAGE(sB3 + (kt) * 128, Bb + _r + 3 * 8192 + w * 1024); } while (0)

#define G1_LOADF(RG, KX) do {                                       \
    _Pragma("unroll") for (int m = 0; m < 4; ++m)                   \
      fA[m] = *(const i32x4*)&Ab[(RG) * 32768 + aBase + m * 2048 + (KX)]; \
    _Pragma("unroll") for (int n = 0; n < 8; ++n)                   \
      fB[n] = *(const i32x4*)&Bb[(RG) * 32768 + bBase + n * 2048 + (KX)]; } while (0)

#define G1_MFMA do { __builtin_amdgcn_s_setprio(1);                 \
    _Pragma("unroll") for (int m = 0; m < 4; ++m)                   \
      _Pragma("unroll") for (int n = 0; n < 8; ++n)                 \
        acc[m][n] = __builtin_amdgcn_mfma_i32_16x16x64_i8(fA[m], fB[n], acc[m][n], 0, 0, 0); \
    __builtin_amdgcn_s_setprio(0); } while (0)

__global__ __launch_bounds__(512) void k_gemm_gu(
    const i8* __restrict__ xq, const i8* __restrict__ wguq,
    const int* __restrict__ seg, const int* __restrict__ segcnt,
    const int* __restrict__ btok, const float* __restrict__ sxg,
    const int* __restrict__ swc_i,
    u16* __restrict__ act)
{
  const int bid = blockIdx.x;
  const int brow = (bid % NROWB) * BM;
  const int bcol = (bid / NROWB) * 256;
  int e;
  if (!seg_lookup(seg, segcnt, brow, e)) return;

  __shared__ __align__(16) i8 Ab[2 * 32768];
  __shared__ __align__(16) i8 Bb[2 * 32768];
  __shared__ float sxl[BM];
  __shared__ float swcl[256];

  const int tid = threadIdx.x;
  const int w = tid >> 6, l = tid & 63;
  const int wm = w >> 1, wn = w & 1;
  const int fr = l & 15, fg = l >> 4;

  if (tid < BM) {
    const int rrow = brow + tid;
    const int tk = (e < 8) ? btok[rrow] : (rrow - RBASE);
    sxl[tid] = sxg[tk];
  } else {
    swcl[tid - 256] = __int_as_float(swc_i[e * 1024 + bcol + (tid - 256)]) * (1.f / 127.f);
  }

  const int rr = w * 8 + (l >> 3);
  const int sw = ((l & 7) ^ (l >> 3)) * 16;
  int tr[4];
#pragma unroll
  for (int j = 0; j < 4; ++j) {
    const int gr = brow + j * 64 + rr;
    tr[j] = (e < 8) ? btok[gr] : (gr - RBASE);
  }
  const i8* sA0 = xq + (size_t)tr[0] * HID + sw;
  const i8* sA1 = xq + (size_t)tr[1] * HID + sw;
  const i8* sA2 = xq + (size_t)tr[2] * HID + sw;
  const i8* sA3 = xq + (size_t)tr[3] * HID + sw;
  const i8* sB0 = wguq + ((size_t)e * 1024 + bcol + 0 * 64 + rr) * HID + sw;
  const i8* sB1 = wguq + ((size_t)e * 1024 + bcol + 1 * 64 + rr) * HID + sw;
  const i8* sB2 = wguq + ((size_t)e * 1024 + bcol + 2 * 64 + rr) * HID + sw;
  const i8* sB3 = wguq + ((size_t)e * 1024 + bcol + 3 * 64 + rr) * HID + sw;

  const int aBase = (wm * 64 + fr) * 128;
  const int bBase = (wn * 128 + fr) * 128;
  const int kx0 = (fg ^ (fr & 7)) * 16;
  const int kx1 = kx0 ^ 64;

  i32x4 acc[4][8];
#pragma unroll
  for (int m = 0; m < 4; ++m)
#pragma unroll
    for (int n = 0; n < 8; ++n) acc[m][n] = (i32x4){0, 0, 0, 0};
  i32x4 fA[4], fB[8];

  const int NKT = HID / 128;
  G1_STG(0);
  asm volatile("s_waitcnt vmcnt(0)" ::: "memory");
  __builtin_amdgcn_s_barrier();
  for (int s = 0; s < NKT; ++s) {
    const int rg = s & 1;
    if (s + 1 < NKT) G1_STG(s + 1);
    G1_LOADF(rg, kx0);
    asm volatile("s_waitcnt lgkmcnt(0)" ::: "memory");
    __builtin_amdgcn_sched_barrier(0);
    G1_MFMA;
    G1_LOADF(rg, kx1);
    asm volatile("s_waitcnt lgkmcnt(0)" ::: "memory");
    __builtin_amdgcn_sched_barrier(0);
    G1_MFMA;
    asm volatile("s_waitcnt vmcnt(0)" ::: "memory");
    __builtin_amdgcn_s_barrier();
  }

#pragma unroll
  for (int m = 0; m < 4; ++m) {
#pragma unroll
    for (int p = 0; p < 4; ++p) {
      const i32x4 gI = acc[m][2 * p], uI = acc[m][2 * p + 1];
      const int col = ((bcol + wn * 128) >> 1) + p * 16 + fr;
      const float swg = swcl[wn * 128 + p * 32 + fr];
      const float swu = swcl[wn * 128 + p * 32 + 16 + fr];
#pragma unroll
      for (int r = 0; r < 4; ++r) {
        const int row_l = wm * 64 + m * 16 + fg * 4 + r;
        const float sx = sxl[row_l];
        const float gate = (float)gI[r] * (sx * swg);
        const float up   = (float)uI[r] * (sx * swu);
        const float sv = gate / (1.f + __expf(-gate));
        act[(size_t)(brow + row_l) * ISZ + col] = f2bf(sv * up);
      }
    }
  }
}

// =================================================================================
// GEMM2 (bf16): mirror of GEMM1. K-slot=64 bf16, 2-ring LDS, ^(row&7) swizzle.
// =================================================================================

#define G2_STG(kt) do { const int _r = ((kt) & 1) * 16384;          \
    STAGE(dA0 + (kt) * 64, As2 + _r + 0 * 4096 + w * 512);          \
    STAGE(dA1 + (kt) * 64, As2 + _r + 1 * 4096 + w * 512);          \
    STAGE(dA2 + (kt) * 64, As2 + _r + 2 * 4096 + w * 512);          \
    STAGE(dA3 + (kt) * 64, As2 + _r + 3 * 4096 + w * 512);          \
    STAGE(dB0 + (kt) * 64, Bs2 + _r + 0 * 4096 + w * 512);          \
    STAGE(dB1 + (kt) * 64, Bs2 + _r + 1 * 4096 + w * 512);          \
    STAGE(dB2 + (kt) * 64, Bs2 + _r + 2 * 4096 + w * 512);          \
    STAGE(dB3 + (kt) * 64, Bs2 + _r + 3 * 4096 + w * 512); } while (0)

#define G2_LOADF(RG, KX) do {                                       \
    _Pragma("unroll") for (int m = 0; m < 4; ++m)                   \
      gA[m] = *(const short8*)&As2[(RG) * 16384 + aBase + m * 1024 + (KX)]; \
    _Pragma("unroll") for (int n = 0; n < 8; ++n)                   \
      gB[n] = *(const short8*)&Bs2[(RG) * 16384 + bBase + n * 1024 + (KX)]; } while (0)

#define G2_MFMA do { __builtin_amdgcn_s_setprio(1);                 \
    _Pragma("unroll") for (int m = 0; m < 4; ++m)                   \
      _Pragma("unroll") for (int n = 0; n < 8; ++n)                 \
        accf[m][n] = __builtin_amdgcn_mfma_f32_16x16x32_bf16(gA[m], gB[n], accf[m][n], 0, 0, 0); \
    __builtin_amdgcn_s_setprio(0); } while (0)

__global__ __launch_bounds__(512) void k_gemm_down(
    const u16* __restrict__ act, const u16* __restrict__ wdT,
    const int* __restrict__ seg, const int* __restrict__ segcnt,
    u16* __restrict__ tmp) {
  const int bid = blockIdx.x;
  const int brow = (bid % NROWB) * BM;
  const int bcol = (bid / NROWB) * 256;
  int e;
  if (!seg_lookup(seg, segcnt, brow, e)) return;

  __shared__ __align__(16) u16 As2[2 * 16384];
  __shared__ __align__(16) u16 Bs2[2 * 16384];

  const int tid = threadIdx.x;
  const int w = tid >> 6, l = tid & 63;
  const int wm = w >> 1, wn = w & 1;
  const int fr = l & 15, fg = l >> 4;

  const int rr = w * 8 + (l >> 3);
  const int sw = ((l & 7) ^ (l >> 3)) * 8;
  const u16* dA0 = act + (size_t)(brow + 0 * 64 + rr) * ISZ + sw;
  const u16* dA1 = act + (size_t)(brow + 1 * 64 + rr) * ISZ + sw;
  const u16* dA2 = act + (size_t)(brow + 2 * 64 + rr) * ISZ + sw;
  const u16* dA3 = act + (size_t)(brow + 3 * 64 + rr) * ISZ + sw;
  const u16* dB0 = wdT + ((size_t)e * 1024 + bcol + 0 * 64 + rr) * ISZ + sw;
  const u16* dB1 = wdT + ((size_t)e * 1024 + bcol + 1 * 64 + rr) * ISZ + sw;
  const u16* dB2 = wdT + ((size_t)e * 1024 + bcol + 2 * 64 + rr) * ISZ + sw;
  const u16* dB3 = wdT + ((size_t)e * 1024 + bcol + 3 * 64 + rr) * ISZ + sw;

  const int aBase = (wm * 64 + fr) * 64;
  const int bBase = (wn * 128 + fr) * 64;
  const int kx0 = (fg ^ (fr & 7)) * 8;
  const int kx1 = kx0 ^ 32;

  f32x4 accf[4][8];
#pragma unroll
  for (int m = 0; m < 4; ++m)
#pragma unroll
    for (int n = 0; n < 8; ++n) accf[m][n] = (f32x4){0.f, 0.f, 0.f, 0.f};
  short8 gA[4], gB[8];

  const int NKT = ISZ / 64;
  G2_STG(0);
  asm volatile("s_waitcnt vmcnt(0)" ::: "memory");
  __builtin_amdgcn_s_barrier();
  for (int s = 0; s < NKT; ++s) {
    const int rg = s & 1;
    if (s + 1 < NKT) G2_STG(s + 1);
    G2_LOADF(rg, kx0);
    asm volatile("s_waitcnt lgkmcnt(0)" ::: "memory");
    __builtin_amdgcn_sched_barrier(0);
    G2_MFMA;
    G2_LOADF(rg, kx1);
    asm volatile("s_waitcnt lgkmcnt(0)" ::: "memory");
    __builtin_amdgcn_sched_barrier(0);
    G2_MFMA;
    asm volatile("s_waitcnt vmcnt(0)" ::: "memory");
    __builtin_amdgcn_s_barrier();
  }

#pragma unroll
  for (int m = 0; m < 4; ++m) {
#pragma unroll
    for (int r = 0; r < 4; ++r) {
      const int row = brow + wm * 64 + m * 16 + fg * 4 + r;
#pragma unroll
      for (int n = 0; n < 8; ++n) {
        const int col = bcol + wn * 128 + n * 16 + fr;
        tmp[(size_t)row * HID + col] = f2bf(accf[m][n][r]);
      }
    }
  }
}

// ---------------- combine: out[t] = tmp[sh] + w0*tmp[s0] + w1*tmp[s1] -----------
__global__ __launch_bounds__(256) void k_combine(
    const u16* __restrict__ tmp, const int* __restrict__ slotmap,
    const float2* __restrict__ wts, float* __restrict__ out) {
  const int idx = blockIdx.x * 256 + threadIdx.x;
  const int t = idx >> 7;
  const int c = (idx & 127) << 3;
  const int s0 = slotmap[2 * t], s1 = slotmap[2 * t + 1];
  const float2 wv = wts[t];
  const short8 a = *(const short8*)(tmp + (size_t)s0 * HID + c);
  const short8 b = *(const short8*)(tmp + (size_t)s1 * HID + c);
  const short8 s = *(const short8*)(tmp + (size_t)(RBASE + t) * HID + c);
  float r[8];
#pragma unroll
  for (int j = 0; j < 8; ++j)
    r[j] = bf2f((u16)s[j]) + wv.x * bf2f((u16)a[j]) + wv.y * bf2f((u16)b[j]);
  float* po = out + (size_t)t * HID + c;
  *(float4*)po       = make_float4(r[0], r[1], r[2], r[3]);
  *(float4*)(po + 4) = make_float4(r[4], r[5], r[6], r[7]);
}

// ---------------- launch ----------------
extern "C" void kernel_launch(void* const* d_in, const int* in_sizes, int n_in,
                              void* d_out, int out_size, void* d_ws, size_t ws_size,
                              hipStream_t stream) {
  const float* x   = (const float*)d_in[0];
  const float* wg  = (const float*)d_in[1];
  const float* wgu = (const float*)d_in[2];
  const float* wdn = (const float*)d_in[3];
  const float* wsg = (const float*)d_in[4];
  const float* wsd = (const float*)d_in[5];
  float* out = (float*)d_out;

  char* ws = (char*)d_ws;
  i8*  xq    = (i8*)ws;   ws += (size_t)T_TOK * HID;
  i8*  wguq  = (i8*)ws;   ws += (size_t)NE * 1024 * HID;
  u16* wdT   = (u16*)ws;  ws += (size_t)NE * HID * ISZ * 2;
  u16* actb  = (u16*)ws;  ws += (size_t)NSLOT * ISZ * 2;
  u16* tmp   = (u16*)ws;  ws += (size_t)NSLOT * HID * 2;
  float* sxg = (float*)ws; ws += (size_t)T_TOK * 4;
  int* swc_i = (int*)ws;  ws += (size_t)NE * 1024 * 4;
  int* eidx  = (int*)ws;  ws += (size_t)T_TOK * 4;
  float2* wt = (float2*)ws; ws += (size_t)T_TOK * 8;
  int* btok  = (int*)ws;  ws += (size_t)RBASE * 4;
  int* smap  = (int*)ws;  ws += (size_t)2 * T_TOK * 4;
  int* seg   = (int*)ws;  ws += 16 * 4;
  int* segc  = (int*)ws;

  k_rw<<<NB_RTR + NB_WAM, 256, 0, stream>>>(
      x, wg, wgu, wsg, xq, sxg, eidx, wt, swc_i);
  k_prep2<<<NB_WGUP + NB_WDN, 256, 0, stream>>>(
      wgu, wsg, wdn, wsd, swc_i, wguq, wdT);
  k_scatter<<<1, 512, 0, stream>>>(eidx, btok, smap, seg, segc);
  k_gemm_gu<<<NROWB * 4, 512, 0, stream>>>(
      xq, wguq, seg, segc, btok, sxg, swc_i, actb);
  k_gemm_down<<<NROWB * 4, 512, 0, stream>>>(actb, wdT, seg, segc, tmp);
  k_combine<<<(T_TOK * HID / 8) / 256, 256, 0, stream>>>(tmp, smap, wt, out);
}